// Round 11
// baseline (2061.141 us; speedup 1.0000x reference)
//
#include <hip/hip_runtime.h>
#include <hip/hip_bf16.h>

typedef __hip_bfloat16 bf16;
typedef __attribute__((ext_vector_type(8))) short short8;
typedef __attribute__((ext_vector_type(4))) short short4v;
typedef __attribute__((ext_vector_type(4))) float f32x4;

__device__ __forceinline__ bf16 f2b(float v){ return __float2bfloat16(v); }
__device__ __forceinline__ unsigned short bfbits(float v){
  union{ bf16 h; unsigned short u; } t; t.h = f2b(v); return t.u;
}
__device__ __forceinline__ float bs2f(short s){
  union{ unsigned u; float f; } t; t.u = ((unsigned)(unsigned short)s) << 16; return t.f;
}

// ---------------- weight repacks ----------------
// w[Cout][Cin][KK] f32 -> o[KK][Cin][Cout] f32  (enc0)
__global__ void repack_tco(const float* __restrict__ w, float* __restrict__ o,
                           int Cout, int Cin, int KK){
  int i = blockIdx.x*256 + threadIdx.x;
  int total = Cout*Cin*KK;
  if (i >= total) return;
  int co = i / (Cin*KK);
  int r  = i - co*(Cin*KK);
  int ci = r / KK;
  int t  = r - ci*KK;
  o[((size_t)t*Cin + ci)*Cout + co] = w[i];
}

// w[Cout][Cin][KK] f32 -> o[Cin][KK][Cout] f32  (out conv: [ci][tap][co])
__global__ void repack_cto(const float* __restrict__ w, float* __restrict__ o,
                           int Cout, int Cin, int KK){
  int i = blockIdx.x*256 + threadIdx.x;
  int total = Cout*Cin*KK;
  if (i >= total) return;
  int co = i / (Cin*KK);
  int r  = i - co*(Cin*KK);
  int ci = r / KK;
  int t  = r - ci*KK;
  o[((size_t)ci*KK + t)*Cout + co] = w[i];
}

// w[Cout][Cin][KK] f32 -> o[tap][Cout/16][Cin/32][64 lanes][8] bf16
// MFMA A-operand FRAGMENT ORDER: lane l = quad*16+n15 holds co=co16*16+n15,
// ci = ci32*32 + quad*8 + e.  af load becomes base + lane*16B (fully coalesced).
__global__ void repack_frag_bf16(const float* __restrict__ w, short* __restrict__ o,
                                 int Cout, int Cin, int KK){
  int i = blockIdx.x*256 + threadIdx.x;
  int total = Cout*Cin*KK;
  if (i >= total) return;
  int co = i / (Cin*KK);
  int r  = i - co*(Cin*KK);
  int ci = r / KK;
  int t  = r - ci*KK;
  int co16 = co >> 4, n15 = co & 15;
  int ci32 = ci >> 5, quad = (ci >> 3) & 3, e = ci & 7;
  size_t off = ((((size_t)t*(Cout>>4) + co16)*(Cin>>5) + ci32)*64 + (quad*16 + n15))*8 + e;
  o[off] = (short)bfbits(w[i]);
}

// codebook [1024][64] f32 -> cbT [64][1024] f32 (coalesced VQ loads)
__global__ void repack_cbT(const float* __restrict__ cb, float* __restrict__ o){
  int i = blockIdx.x*256 + threadIdx.x;
  if (i >= 65536) return;
  int c = i >> 6, d = i & 63;
  o[(size_t)d*1024 + c] = cb[i];
}

// ---------------- enc0: conv k=4 s=2 p=1, NCHW f32 in -> NHWC bf16 out ----------------
__global__ __launch_bounds__(256) void conv_enc0(
    const float* __restrict__ x, const float* __restrict__ wp,  // [tap][ci][co]
    const float* __restrict__ bias, short* __restrict__ y)      // NHWC [128][128][128]
{
  int t = blockIdx.x*256 + threadIdx.x;
  int oh  = t >> 5;
  int ow0 = (t & 31) * 4;
  int co0 = blockIdx.y * 8;
  int n   = blockIdx.z;
  float acc[8][4];
  #pragma unroll
  for (int j=0;j<8;j++){
    float bv = bias[co0+j];
    #pragma unroll
    for (int o=0;o<4;o++) acc[j][o] = bv;
  }
  const float* xn = x + (size_t)n*3*65536;
  #pragma unroll
  for (int ci=0; ci<3; ci++){
    const float* xc = xn + (size_t)ci*65536;
    #pragma unroll
    for (int kh=0; kh<4; kh++){
      int ih = 2*oh - 1 + kh;
      float xv[12];
      if ((unsigned)ih < 256u){
        #pragma unroll
        for (int c2=0; c2<6; c2++){
          int col = 2*ow0 - 2 + 2*c2;
          if (col >= 0 && col < 256){
            float2 v = *(const float2*)(xc + (size_t)ih*256 + col);
            xv[2*c2] = v.x; xv[2*c2+1] = v.y;
          } else { xv[2*c2] = 0.f; xv[2*c2+1] = 0.f; }
        }
      } else {
        #pragma unroll
        for (int k=0;k<12;k++) xv[k] = 0.f;
      }
      #pragma unroll
      for (int kw=0; kw<4; kw++){
        const float* wr = wp + (size_t)((kh*4+kw)*3 + ci)*128 + co0;  // uniform
        #pragma unroll
        for (int j=0;j<8;j++){
          float wf = wr[j];
          #pragma unroll
          for (int o=0;o<4;o++)
            acc[j][o] = fmaf(xv[2*o+kw+1], wf, acc[j][o]);
        }
      }
    }
  }
  #pragma unroll
  for (int o=0;o<4;o++){
    short8 pk;
    #pragma unroll
    for (int j=0;j<8;j++) pk[j] = (short)bfbits(fmaxf(acc[j][o], 0.f));
    *(short8*)&y[(((size_t)n*128 + oh)*128 + (ow0+o))*128 + co0] = pk;
  }
}

// ---------------- enc1/enc2: conv k=4 s=2 p=1 MFMA, NHWC, 2cs x 2ss waves ----------------
// dbuf LDS, one barrier per chunk; fragment-order weights; conflict-free LDS layout;
// staging offsets hoisted out of the K-loop (int32 offsets, -1 = OOB halo).
template<int TS>
__global__ __launch_bounds__(256) void conv_enc_mfma(
    const short* __restrict__ x, const short* __restrict__ wb,
    const float* __restrict__ bias, short* __restrict__ y,
    int Cin, int Hin, int Win, int Cout)
{
  constexpr int SHW  = TS/32;
  constexpr int COB  = (4/SHW)*32;
  constexpr int CLS  = 2*TS + 2;
  constexpr int CPH  = TS + 1;
  constexpr int NST  = 4*CLS*4;
  constexpr int NIT  = (NST + 255)/256;
  __shared__ __align__(16) short ldsA[4*4*2*CPH*8];
  __shared__ __align__(16) short ldsB[4*4*2*CPH*8];

  int tid = threadIdx.x;
  int w = tid >> 6, lane = tid & 63;
  int sh = w % SHW, ch = w / SHW;
  int n15 = lane & 15, quad = lane >> 4;
  int oh = blockIdx.y;
  int j0 = blockIdx.x * TS;
  int nct = Cout / COB;
  int ct = blockIdx.z % nct;
  int nimg = blockIdx.z / nct;
  int co_base = ct*COB + ch*32;
  int Hout = Hin >> 1, Wout = Win >> 1;
  int row_org = 2*oh - 1;
  int col_org = 2*j0 - 1;
  int nco16 = Cout >> 4, nci32 = Cin >> 5;

  f32x4 acc[2][2];
  #pragma unroll
  for (int cs=0; cs<2; cs++){
    int cb = co_base + cs*16 + quad*4;
    f32x4 bv = {bias[cb], bias[cb+1], bias[cb+2], bias[cb+3]};
    acc[cs][0] = bv; acc[cs][1] = bv;
  }

  const short* xn = x + (size_t)nimg*Hin*Win*Cin;

  // hoisted staging offsets (chunk-invariant; only ci0 advances)
  int goff[NIT], lo[NIT];
  #pragma unroll
  for (int k=0;k<NIT;k++){
    goff[k] = -1; lo[k] = 0;
    int idx = tid + k*256;
    if (idx < NST){
      int r   = idx / (CLS*4);
      int rem = idx - r*(CLS*4);
      int c   = rem >> 2;
      int q4  = rem & 3;
      lo[k] = ((((q4*4 + r)*2 + (c&1))*CPH) + (c>>1))*8;
      int gi = row_org + r, gj = col_org + c;
      if ((unsigned)gi < (unsigned)Hin && (unsigned)gj < (unsigned)Win)
        goff[k] = (gi*Win + gj)*Cin + q4*8;
    }
  }

  auto stage = [&](short* dst, int ci0){
    #pragma unroll
    for (int k=0;k<NIT;k++){
      if (tid + k*256 < NST){
        short8 v = {0,0,0,0,0,0,0,0};
        if (goff[k] >= 0) v = *(const short8*)(xn + goff[k] + ci0);
        *(short8*)&dst[lo[k]] = v;
      }
    }
  };

  auto compute = [&](const short* lds, int ci0){
    int ci32 = ci0 >> 5;
    #pragma unroll
    for (int kh=0; kh<4; kh++){
      short8 bfr[4][2];
      #pragma unroll
      for (int kw=0; kw<4; kw++)
        #pragma unroll
        for (int ss=0; ss<2; ss++){
          int X = sh*32 + ss*16 + n15;
          bfr[kw][ss] = *(const short8*)&lds[((((quad*4 + kh)*2 + (kw&1))*CPH) + X + (kw>>1))*8];
        }
      #pragma unroll
      for (int kw=0; kw<4; kw++){
        int tap = kh*4 + kw;
        #pragma unroll
        for (int cs=0; cs<2; cs++){
          int co16 = (co_base + cs*16) >> 4;
          short8 af = *(const short8*)(wb +
              ((((size_t)tap*nco16 + co16)*nci32 + ci32)*64 + lane)*8);
          #pragma unroll
          for (int ss=0; ss<2; ss++)
            acc[cs][ss] = __builtin_amdgcn_mfma_f32_16x16x32_bf16(af, bfr[kw][ss], acc[cs][ss], 0,0,0);
        }
      }
    }
  };

  int nch = Cin >> 5;
  stage(ldsA, 0);
  __syncthreads();
  for (int t = 0; t < nch; t++){
    const short* cur = (t & 1) ? ldsB : ldsA;
    short*       nxt = (t & 1) ? ldsA : ldsB;
    if (t+1 < nch) stage(nxt, (t+1)*32);
    compute(cur, t*32);
    __syncthreads();
  }

  #pragma unroll
  for (int cs=0; cs<2; cs++)
    #pragma unroll
    for (int ss=0; ss<2; ss++){
      int jj = j0 + sh*32 + ss*16 + n15;
      short4v pk;
      #pragma unroll
      for (int r=0;r<4;r++) pk[r] = (short)bfbits(fmaxf(acc[cs][ss][r], 0.f));
      *(short4v*)&y[(((size_t)nimg*Hout + oh)*Wout + jj)*Cout + co_base + cs*16 + quad*4] = pk;
    }
}

// ---------------- proj: 1x1 conv as MFMA GEMM; z -> NCHW f32 (d_out) + NHWC f32 (ws) ----------------
// wb fragment order: [4 co16][16 ci32][64][8]
__global__ __launch_bounds__(256) void proj_mfma(
    const short* __restrict__ x, const short* __restrict__ wb,
    const float* __restrict__ bias, float* __restrict__ z_nchw,
    float* __restrict__ z_nhwc)
{
  int tid = threadIdx.x;
  int w = tid >> 6, lane = tid & 63;
  int n15 = lane & 15, quad = lane >> 4;
  int sp0 = blockIdx.x*64 + w*16;
  int nimg = blockIdx.y;
  f32x4 acc[4];
  #pragma unroll
  for (int cs=0; cs<4; cs++){
    int cb = cs*16 + quad*4;
    acc[cs] = f32x4{bias[cb], bias[cb+1], bias[cb+2], bias[cb+3]};
  }
  const short* xs = x + ((size_t)nimg*1024 + sp0 + n15)*512;
  for (int ci0=0; ci0<512; ci0+=32){
    short8 bfr = *(const short8*)(xs + ci0 + quad*8);
    #pragma unroll
    for (int cs=0; cs<4; cs++){
      short8 af = *(const short8*)(wb + ((((size_t)cs*16) + (ci0>>5))*64 + lane)*8);
      acc[cs] = __builtin_amdgcn_mfma_f32_16x16x32_bf16(af, bfr, acc[cs], 0,0,0);
    }
  }
  int sp = sp0 + n15;
  #pragma unroll
  for (int cs=0; cs<4; cs++){
    #pragma unroll
    for (int r=0;r<4;r++)
      z_nchw[(size_t)nimg*65536 + (size_t)(cs*16+quad*4+r)*1024 + sp] = acc[cs][r];
    *(f32x4*)&z_nhwc[((size_t)nimg*1024 + sp)*64 + cs*16 + quad*4] = acc[cs];
  }
}

// ---------------- VQ: per-wave argmin over 1024 codes (NHWC z) ----------------
// cbT [64 dims][1024 codes]: lane l owns codes g*256+4l..+3 -> float4 loads at
// base+lane*16B, fully coalesced.  Distance accumulates dims 0..63 in one
// sequential fmaf chain (same order as before) -> bitwise-identical distances.
__global__ void vq_argmin(const float* __restrict__ zf, const float* __restrict__ cbf,
                          const float* __restrict__ cbT,
                          float* __restrict__ zq, short* __restrict__ zqst)
{
  __shared__ float lz[4][64];
  int t = threadIdx.x;
  int q = t >> 6, l = t & 63;
  int p = blockIdx.x*4 + q;
  int n = p >> 10, hw = p & 1023;
  size_t nhbase = ((size_t)n*1024 + hw)*64;
  float zl = zf[nhbase + l];
  lz[q][l] = zl;
  __syncthreads();
  const float* zv = &lz[q][0];

  f32x4 acc[4];
  #pragma unroll
  for (int g=0; g<4; g++) acc[g] = f32x4{0.f,0.f,0.f,0.f};
  const float* rowb = cbT + l*4;
  for (int d = 0; d < 64; d++){
    float zd = zv[d];
    const float* row = rowb + (size_t)d*1024;
    #pragma unroll
    for (int g=0; g<4; g++){
      float4 cv = *(const float4*)(row + g*256);
      float t0 = zd - cv.x; acc[g][0] = fmaf(t0,t0,acc[g][0]);
      float t1 = zd - cv.y; acc[g][1] = fmaf(t1,t1,acc[g][1]);
      float t2 = zd - cv.z; acc[g][2] = fmaf(t2,t2,acc[g][2]);
      float t3 = zd - cv.w; acc[g][3] = fmaf(t3,t3,acc[g][3]);
    }
  }
  // per-lane scan in ascending code order (strict < keeps earliest index)
  float best = 3.0e38f; int bi = 0;
  #pragma unroll
  for (int g=0; g<4; g++){
    int c0 = g*256 + l*4;
    #pragma unroll
    for (int j=0; j<4; j++)
      if (acc[g][j] < best){ best = acc[g][j]; bi = c0 + j; }
  }
  // cross-lane min with index tie-break (smaller index wins on equal distance)
  #pragma unroll
  for (int off = 32; off > 0; off >>= 1){
    float od = __shfl_down(best, off, 64);
    int   oi = __shfl_down(bi,  off, 64);
    if (od < best || (od == best && oi < bi)){ best = od; bi = oi; }
  }
  bi = __shfl(bi, 0, 64);
  float qv = cbf[(size_t)bi*64 + l];
  zq[(size_t)n*65536 + (size_t)l*1024 + hw] = qv;
  zqst[nhbase + l] = (short)bfbits(zl + (qv - zl));
}

// ---------------- decoder: convT k=4 s=2 MFMA, NHWC — PHASE-SPLIT ----------------
// One block per sub-pixel phase (ph,pw); fragment-order weights; conflict-free
// LDS layout [q4][r][CPC][8]; staging offsets hoisted (int32, -1 = OOB).
// Accumulation order identical to r0 -> bitwise-identical.
template<int TS>
__global__ __launch_bounds__(256) void convT_mfma(
    const short* __restrict__ x, const short* __restrict__ wb,
    const float* __restrict__ bias, short* __restrict__ y,
    int Cin, int Hin, int Win, int Cout, int relu)
{
  constexpr int SHW  = TS/32;
  constexpr int COB  = (4/SHW)*32;
  constexpr int CPC  = TS + 1;          // staged cols per phase
  constexpr int NST  = 2*CPC*4;
  constexpr int NIT  = (NST + 255)/256;
  __shared__ __align__(16) short ldsA[4*2*CPC*8];
  __shared__ __align__(16) short ldsB[4*2*CPC*8];

  int tid = threadIdx.x;
  int w = tid >> 6, lane = tid & 63;
  int sh = w % SHW, ch = w / SHW;
  int n15 = lane & 15, quad = lane >> 4;
  int i0 = blockIdx.y;
  int j0 = blockIdx.x * TS;
  int nct = Cout / COB;
  int zz = blockIdx.z;
  int ph = (zz >> 1) & 1, pw = zz & 1;
  int ct = (zz >> 2) % nct;
  int nimg = (zz >> 2) / nct;
  int co_base = ct*COB + ch*32;
  int nco16 = Cout >> 4, nci32 = Cin >> 5;

  f32x4 acc[2][2];
  #pragma unroll
  for (int cs=0; cs<2; cs++){
    int cb = co_base + cs*16 + quad*4;
    f32x4 bv = {bias[cb], bias[cb+1], bias[cb+2], bias[cb+3]};
    acc[cs][0] = bv; acc[cs][1] = bv;
  }

  const short* xn = x + (size_t)nimg*Hin*Win*Cin;
  int row_org = i0 - 1 + ph;
  int col_org = j0 - 1 + pw;

  // hoisted staging offsets (chunk-invariant; only ci0 advances)
  int goff[NIT], lo[NIT];
  #pragma unroll
  for (int k=0;k<NIT;k++){
    goff[k] = -1; lo[k] = 0;
    int idx = tid + k*256;
    if (idx < NST){
      int r   = idx / (CPC*4);
      int rem = idx - r*(CPC*4);
      int c   = rem >> 2;
      int q4  = rem & 3;
      lo[k] = ((q4*2 + r)*CPC + c)*8;
      int gi = row_org + r, gj = col_org + c;
      if ((unsigned)gi < (unsigned)Hin && (unsigned)gj < (unsigned)Win)
        goff[k] = (gi*Win + gj)*Cin + q4*8;
    }
  }

  auto stage = [&](short* dst, int ci0){
    #pragma unroll
    for (int k=0;k<NIT;k++){
      if (tid + k*256 < NST){
        short8 v = {0,0,0,0,0,0,0,0};
        if (goff[k] >= 0) v = *(const short8*)(xn + goff[k] + ci0);
        *(short8*)&dst[lo[k]] = v;
      }
    }
  };

  auto compute = [&](const short* lds, int ci0){
    int ci32 = ci0 >> 5;
    short8 br[2][2][2];               // [u][v][ss]
    #pragma unroll
    for (int u=0; u<2; u++)
      #pragma unroll
      for (int v=0; v<2; v++)
        #pragma unroll
        for (int ss=0; ss<2; ss++){
          int col = sh*32 + ss*16 + n15 + v;
          br[u][v][ss] = *(const short8*)&lds[((quad*2 + u)*CPC + col)*8];
        }
    #pragma unroll
    for (int u=0; u<2; u++)
      #pragma unroll
      for (int v=0; v<2; v++){
        int tap = (ph + 2*u)*4 + (pw + 2*v);
        #pragma unroll
        for (int cs=0; cs<2; cs++){
          int co16 = (co_base + cs*16) >> 4;
          short8 af = *(const short8*)(wb +
              ((((size_t)tap*nco16 + co16)*nci32 + ci32)*64 + lane)*8);
          #pragma unroll
          for (int ss=0; ss<2; ss++)
            acc[cs][ss] = __builtin_amdgcn_mfma_f32_16x16x32_bf16(af, br[u][v][ss], acc[cs][ss], 0,0,0);
        }
      }
  };

  int nch = Cin >> 5;
  stage(ldsA, 0);
  __syncthreads();
  for (int t = 0; t < nch; t++){
    const short* cur = (t & 1) ? ldsB : ldsA;
    short*       nxt = (t & 1) ? ldsA : ldsB;
    if (t+1 < nch) stage(nxt, (t+1)*32);
    compute(cur, t*32);
    __syncthreads();
  }

  int Hout = Hin*2, Wout = Win*2;
  #pragma unroll
  for (int cs=0; cs<2; cs++)
    #pragma unroll
    for (int ss=0; ss<2; ss++){
      int jj = j0 + sh*32 + ss*16 + n15;
      short4v pk;
      #pragma unroll
      for (int r=0;r<4;r++){
        float v2 = acc[cs][ss][r];
        if (relu) v2 = fmaxf(v2, 0.f);
        pk[r] = (short)bfbits(v2);
      }
      *(short4v*)&y[(((size_t)nimg*Hout + 2*i0+ph)*Wout + 2*jj+pw)*Cout + co_base + cs*16 + quad*4] = pk;
    }
}

// ---------------- out conv: 3x3 p=1 s=1, NHWC in -> NCHW f32 out ----------------
__global__ __launch_bounds__(256) void conv3x3_out3(
    const short* __restrict__ x, const float* __restrict__ wct,  // [ci][9][3]
    const float* __restrict__ bias, float* __restrict__ y)
{
  __shared__ __align__(16) short xl[6*66*16];
  int tid = threadIdx.x;
  int row = tid >> 6;
  int col = tid & 63;
  int j0 = blockIdx.x*64;
  int r0 = blockIdx.y*4;
  int n  = blockIdx.z;
  const short* xn = x + (size_t)n*65536*128;
  float acc[3] = {bias[0], bias[1], bias[2]};
  for (int g=0; g<8; g++){
    int cig = g*16;
    __syncthreads();
    for (int idx = tid; idx < 792; idx += 256){
      int r = idx / 132;
      int rem = idx - r*132;
      int c = rem >> 1;
      int h = rem & 1;
      int gi = r0 - 1 + r, gj = j0 - 1 + c;
      short8 v = {0,0,0,0,0,0,0,0};
      if ((unsigned)gi < 256u && (unsigned)gj < 256u)
        v = *(const short8*)(xn + ((size_t)gi*256 + gj)*128 + cig + h*8);
      *(short8*)&xl[(r*66 + c)*16 + h*8] = v;
    }
    __syncthreads();
    #pragma unroll
    for (int half=0; half<2; half++){
      short8 xv[9];
      #pragma unroll
      for (int dr=0; dr<3; dr++)
        #pragma unroll
        for (int dc=0; dc<3; dc++)
          xv[dr*3+dc] = *(const short8*)&xl[((row+dr)*66 + col+dc)*16 + half*8];
      #pragma unroll
      for (int k=0;k<8;k++){
        const float* wr = wct + (size_t)(cig + half*8 + k)*27;   // uniform
        #pragma unroll
        for (int tp=0; tp<9; tp++){
          float xf = bs2f(xv[tp][k]);
          acc[0] = fmaf(xf, wr[tp*3+0], acc[0]);
          acc[1] = fmaf(xf, wr[tp*3+1], acc[1]);
          acc[2] = fmaf(xf, wr[tp*3+2], acc[2]);
        }
      }
    }
  }
  size_t obase = (size_t)n*3*65536 + (size_t)(r0+row)*256 + j0 + col;
  y[obase]          = acc[0];
  y[obase + 65536]  = acc[1];
  y[obase + 131072] = acc[2];
}

// ---------------- workspace layout (bytes) ----------------
static const size_t W_WENC0  = 0;           //  24,576 f32 [tap][ci][co]
static const size_t W_WPROJB = 24576;       //  65,536 bf16 fragment-order
static const size_t W_WOUT   = 90112;       //  13,824 f32 [ci][tap][co]
static const size_t W_E1B    = 103936;      //  1,048,576 bf16 fragment-order
static const size_t W_E2B    = 1152512;     //  4,194,304
static const size_t W_D0B    = 5346816;     //  1,048,576
static const size_t W_D1B    = 6395392;     //  4,194,304
static const size_t W_D2B    = 10589696;    //  1,048,576
static const size_t W_CBT    = 11638272;    //  262,144 f32 codebook^T [64][1024]
static const size_t W_BYTES  = 11900416;
// per-image activations (NHWC, lifetime-aliased):
//   A 16MiB (h0 4M / d2 16M), Bg 8MiB (h1 2M / d1 8M), C 4MiB (h2 1M / d0 4M),
//   zf f32 256K, zqs bf16 128K
static const size_t PER_IMG = 29753344;

extern "C" void kernel_launch(void* const* d_in, const int* in_sizes, int n_in,
                              void* d_out, int out_size, void* d_ws, size_t ws_size,
                              hipStream_t stream)
{
  const float* x      = (const float*)d_in[0];
  const float* enc_w0 = (const float*)d_in[1];
  const float* enc_b0 = (const float*)d_in[2];
  const float* enc_w1 = (const float*)d_in[3];
  const float* enc_b1 = (const float*)d_in[4];
  const float* enc_w2 = (const float*)d_in[5];
  const float* enc_b2 = (const float*)d_in[6];
  const float* proj_w = (const float*)d_in[7];
  const float* proj_b = (const float*)d_in[8];
  const float* dec_w0 = (const float*)d_in[9];
  const float* dec_b0 = (const float*)d_in[10];
  const float* dec_w1 = (const float*)d_in[11];
  const float* dec_b1 = (const float*)d_in[12];
  const float* dec_w2 = (const float*)d_in[13];
  const float* dec_b2 = (const float*)d_in[14];
  const float* out_w  = (const float*)d_in[15];
  const float* out_b  = (const float*)d_in[16];
  const float* cb     = (const float*)d_in[17];

  float* out    = (float*)d_out;
  float* recon  = out;
  float* z_out  = out + 3145728;
  float* zq_out = out + 4194304;

  char* ws = (char*)d_ws;
  float* wenc0  = (float*)(ws + W_WENC0);
  short* wprojb = (short*)(ws + W_WPROJB);
  float* wout   = (float*)(ws + W_WOUT);
  short* we1b   = (short*)(ws + W_E1B);
  short* we2b   = (short*)(ws + W_E2B);
  short* wd0b   = (short*)(ws + W_D0B);
  short* wd1b   = (short*)(ws + W_D1B);
  short* wd2b   = (short*)(ws + W_D2B);
  float* cbT    = (float*)(ws + W_CBT);

  int B = 16;
  while (B > 1 && W_BYTES + (size_t)B*PER_IMG > ws_size) B >>= 1;

  char* act = ws + W_BYTES;
  size_t szA  = (size_t)B*16777216;
  size_t szBg = (size_t)B*8388608;
  size_t szC  = (size_t)B*4194304;
  short* h0  = (short*)(act);
  short* d2  = (short*)(act);
  short* h1  = (short*)(act + szA);
  short* d1  = (short*)(act + szA);
  short* h2  = (short*)(act + szA + szBg);
  short* d0  = (short*)(act + szA + szBg);
  float* zf  = (float*)(act + szA + szBg + szC);
  short* zqs = (short*)(act + szA + szBg + szC + (size_t)B*262144);

  auto nb = [](int total){ return dim3((unsigned)((total + 255) / 256)); };

  repack_tco<<<nb(128*3*16),  256, 0, stream>>>(enc_w0, wenc0, 128, 3, 16);
  repack_frag_bf16<<<nb(64*512),   256, 0, stream>>>(proj_w, wprojb, 64, 512, 1);
  repack_cto<<<nb(3*128*9),   256, 0, stream>>>(out_w, wout, 3, 128, 9);
  repack_frag_bf16<<<nb(256*128*16),256, 0, stream>>>(enc_w1, we1b, 256, 128, 16);
  repack_frag_bf16<<<nb(512*256*16),256, 0, stream>>>(enc_w2, we2b, 512, 256, 16);
  repack_frag_bf16<<<nb(512*64*16), 256, 0, stream>>>(dec_w0, wd0b, 512, 64, 16);
  repack_frag_bf16<<<nb(256*512*16),256, 0, stream>>>(dec_w1, wd1b, 256, 512, 16);
  repack_frag_bf16<<<nb(128*256*16),256, 0, stream>>>(dec_w2, wd2b, 128, 256, 16);
  repack_cbT<<<nb(65536), 256, 0, stream>>>(cb, cbT);

  for (int n0 = 0; n0 < 16; n0 += B){
    const float* xc  = x      + (size_t)n0*3*65536;
    float* reconc    = recon  + (size_t)n0*3*65536;
    float* z_outc    = z_out  + (size_t)n0*65536;
    float* zq_outc   = zq_out + (size_t)n0*65536;

    // encoder (NHWC activations)
    conv_enc0<<<dim3(16,16,B), 256, 0, stream>>>(xc, wenc0, enc_b0, h0);
    conv_enc_mfma<32><<<dim3(2, 64, B*2), 256, 0, stream>>>(
        h0, we1b, enc_b1, h1, 128, 128, 128, 256);
    conv_enc_mfma<32><<<dim3(1, 32, B*4), 256, 0, stream>>>(
        h1, we2b, enc_b2, h2, 256, 64, 64, 512);
    proj_mfma<<<dim3(16, B), 256, 0, stream>>>(h2, wprojb, proj_b, z_outc, zf);

    vq_argmin<<<dim3(256*B), 256, 0, stream>>>(zf, cb, cbT, zq_outc, zqs);

    // decoder (NHWC), phase-split: z = B * nct * 4 phases
    convT_mfma<32><<<dim3(1, 32, B*4*4), 256, 0, stream>>>(
        zqs, wd0b, dec_b0, d0, 64, 32, 32, 512, 1);      // nct=4 (COB=128)
    convT_mfma<64><<<dim3(1, 64, B*4*4), 256, 0, stream>>>(
        d0, wd1b, dec_b1, d1, 512, 64, 64, 256, 1);      // nct=4 (COB=64)
    convT_mfma<64><<<dim3(2, 128, B*2*4), 256, 0, stream>>>(
        d1, wd2b, dec_b2, d2, 256, 128, 128, 128, 1);    // nct=2 (COB=64)

    conv3x3_out3<<<dim3(4, 64, B), 256, 0, stream>>>(d2, wout, out_b, reconc);
  }
}

// Round 12
// 1940.093 us; speedup vs baseline: 1.0624x; 1.0624x over previous
//
#include <hip/hip_runtime.h>
#include <hip/hip_bf16.h>

typedef __hip_bfloat16 bf16;
typedef __attribute__((ext_vector_type(8))) short short8;
typedef __attribute__((ext_vector_type(4))) short short4v;
typedef __attribute__((ext_vector_type(4))) float f32x4;

__device__ __forceinline__ bf16 f2b(float v){ return __float2bfloat16(v); }
__device__ __forceinline__ unsigned short bfbits(float v){
  union{ bf16 h; unsigned short u; } t; t.h = f2b(v); return t.u;
}
__device__ __forceinline__ float bs2f(short s){
  union{ unsigned u; float f; } t; t.u = ((unsigned)(unsigned short)s) << 16; return t.f;
}

// ---------------- fused weight repack (single launch, 9 jobs) ----------------
// MFMA A-operand fragment order: [tap][Cout/16][Cin/32][64 lanes][8] bf16,
// lane l = quad*16+n15 holds co=co16*16+n15, ci=ci32*32+quad*8+e.
__device__ __forceinline__ void frag_one(const float* __restrict__ w, short* __restrict__ o,
                                         int Cout, int Cin, int KK, int i){
  int co = i / (Cin*KK);
  int r  = i - co*(Cin*KK);
  int ci = r / KK;
  int t  = r - ci*KK;
  int co16 = co >> 4, n15 = co & 15;
  int ci32 = ci >> 5, quad = (ci >> 3) & 3, e = ci & 7;
  size_t off = ((((size_t)t*(Cout>>4) + co16)*(Cin>>5) + ci32)*64 + (quad*16 + n15))*8 + e;
  o[off] = (short)bfbits(w[i]);
}

__global__ __launch_bounds__(256) void repack_all(
    const float* __restrict__ enc_w0, float* __restrict__ wenc0,
    const float* __restrict__ out_w,  float* __restrict__ wout,
    const float* __restrict__ proj_w, short* __restrict__ wprojb,
    const float* __restrict__ w_e1, short* __restrict__ we1b,
    const float* __restrict__ w_e2, short* __restrict__ we2b,
    const float* __restrict__ w_d0, short* __restrict__ wd0b,
    const float* __restrict__ w_d1, short* __restrict__ wd1b,
    const float* __restrict__ w_d2, short* __restrict__ wd2b,
    const float* __restrict__ cb,   float* __restrict__ cbT)
{
  int gid = blockIdx.x*256 + threadIdx.x;
  int stp = gridDim.x*256;

  // enc0: w[128][3][16] f32 -> [tap][ci][co] f32
  for (int i = gid; i < 128*3*16; i += stp){
    int co = i / 48, r = i - co*48, ci = r >> 4, t = r & 15;
    wenc0[((size_t)t*3 + ci)*128 + co] = enc_w0[i];
  }
  // out conv: w[3][128][9] f32 -> [ci][tap][co] f32
  for (int i = gid; i < 3*128*9; i += stp){
    int co = i / (128*9), r = i - co*(128*9), ci = r / 9, t = r - ci*9;
    wout[((size_t)ci*9 + t)*3 + co] = out_w[i];
  }
  // proj: [64][512] -> fragment order (KK=1)
  for (int i = gid; i < 64*512; i += stp) frag_one(proj_w, wprojb, 64, 512, 1, i);
  // enc1/enc2/dec0/dec1/dec2: fragment order (KK=16)
  for (int i = gid; i < 256*128*16; i += stp) frag_one(w_e1, we1b, 256, 128, 16, i);
  for (int i = gid; i < 512*256*16; i += stp) frag_one(w_e2, we2b, 512, 256, 16, i);
  for (int i = gid; i < 512*64*16;  i += stp) frag_one(w_d0, wd0b, 512, 64, 16, i);
  for (int i = gid; i < 256*512*16; i += stp) frag_one(w_d1, wd1b, 256, 512, 16, i);
  for (int i = gid; i < 128*256*16; i += stp) frag_one(w_d2, wd2b, 128, 256, 16, i);
  // codebook [1024][64] -> cbT [64][1024]
  for (int i = gid; i < 65536; i += stp){
    int c = i >> 6, d = i & 63;
    cbT[(size_t)d*1024 + c] = cb[i];
  }
}

// ---------------- enc0: conv k=4 s=2 p=1, NCHW f32 in -> NHWC bf16 out ----------------
__global__ __launch_bounds__(256) void conv_enc0(
    const float* __restrict__ x, const float* __restrict__ wp,  // [tap][ci][co]
    const float* __restrict__ bias, short* __restrict__ y)      // NHWC [128][128][128]
{
  int t = blockIdx.x*256 + threadIdx.x;
  int oh  = t >> 5;
  int ow0 = (t & 31) * 4;
  int co0 = blockIdx.y * 8;
  int n   = blockIdx.z;
  float acc[8][4];
  #pragma unroll
  for (int j=0;j<8;j++){
    float bv = bias[co0+j];
    #pragma unroll
    for (int o=0;o<4;o++) acc[j][o] = bv;
  }
  const float* xn = x + (size_t)n*3*65536;
  #pragma unroll
  for (int ci=0; ci<3; ci++){
    const float* xc = xn + (size_t)ci*65536;
    #pragma unroll
    for (int kh=0; kh<4; kh++){
      int ih = 2*oh - 1 + kh;
      float xv[12];
      if ((unsigned)ih < 256u){
        #pragma unroll
        for (int c2=0; c2<6; c2++){
          int col = 2*ow0 - 2 + 2*c2;
          if (col >= 0 && col < 256){
            float2 v = *(const float2*)(xc + (size_t)ih*256 + col);
            xv[2*c2] = v.x; xv[2*c2+1] = v.y;
          } else { xv[2*c2] = 0.f; xv[2*c2+1] = 0.f; }
        }
      } else {
        #pragma unroll
        for (int k=0;k<12;k++) xv[k] = 0.f;
      }
      #pragma unroll
      for (int kw=0; kw<4; kw++){
        const float* wr = wp + (size_t)((kh*4+kw)*3 + ci)*128 + co0;  // uniform
        #pragma unroll
        for (int j=0;j<8;j++){
          float wf = wr[j];
          #pragma unroll
          for (int o=0;o<4;o++)
            acc[j][o] = fmaf(xv[2*o+kw+1], wf, acc[j][o]);
        }
      }
    }
  }
  #pragma unroll
  for (int o=0;o<4;o++){
    short8 pk;
    #pragma unroll
    for (int j=0;j<8;j++) pk[j] = (short)bfbits(fmaxf(acc[j][o], 0.f));
    *(short8*)&y[(((size_t)n*128 + oh)*128 + (ow0+o))*128 + co0] = pk;
  }
}

// ---------------- enc1/enc2: conv k=4 s=2 p=1 MFMA, NHWC, 2cs x 2ss waves ----------------
// dbuf LDS, one barrier per chunk; fragment-order weights.
// LDS layout [q4][kh][parity][CPH][8]: stride-2 kw-reads become consecutive
// 16B blocks per lane -> bank-conflict-free ds_read_b128 / ds_write_b128.
template<int TS>
__global__ __launch_bounds__(256) void conv_enc_mfma(
    const short* __restrict__ x, const short* __restrict__ wb,
    const float* __restrict__ bias, short* __restrict__ y,
    int Cin, int Hin, int Win, int Cout)
{
  constexpr int SHW  = TS/32;
  constexpr int COB  = (4/SHW)*32;
  constexpr int CLS  = 2*TS + 2;
  constexpr int CPH  = TS + 1;
  __shared__ __align__(16) short ldsA[4*4*2*CPH*8];
  __shared__ __align__(16) short ldsB[4*4*2*CPH*8];

  int tid = threadIdx.x;
  int w = tid >> 6, lane = tid & 63;
  int sh = w % SHW, ch = w / SHW;
  int n15 = lane & 15, quad = lane >> 4;
  int oh = blockIdx.y;
  int j0 = blockIdx.x * TS;
  int nct = Cout / COB;
  int ct = blockIdx.z % nct;
  int nimg = blockIdx.z / nct;
  int co_base = ct*COB + ch*32;
  int Hout = Hin >> 1, Wout = Win >> 1;
  int row_org = 2*oh - 1;
  int col_org = 2*j0 - 1;
  int nco16 = Cout >> 4, nci32 = Cin >> 5;

  f32x4 acc[2][2];
  #pragma unroll
  for (int cs=0; cs<2; cs++){
    int cb = co_base + cs*16 + quad*4;
    f32x4 bv = {bias[cb], bias[cb+1], bias[cb+2], bias[cb+3]};
    acc[cs][0] = bv; acc[cs][1] = bv;
  }

  const short* xn = x + (size_t)nimg*Hin*Win*Cin;

  auto stage = [&](short* dst, int ci0){
    for (int idx = tid; idx < 4*CLS*4; idx += 256){
      int r   = idx / (CLS*4);
      int rem = idx - r*(CLS*4);
      int c   = rem >> 2;
      int q4  = rem & 3;
      int gi = row_org + r, gj = col_org + c;
      short8 v = {0,0,0,0,0,0,0,0};
      if ((unsigned)gi < (unsigned)Hin && (unsigned)gj < (unsigned)Win)
        v = *(const short8*)(xn + ((size_t)gi*Win + gj)*Cin + ci0 + q4*8);
      *(short8*)&dst[((((q4*4 + r)*2 + (c&1))*CPH) + (c>>1))*8] = v;
    }
  };

  auto compute = [&](const short* lds, int ci0){
    int ci32 = ci0 >> 5;
    #pragma unroll
    for (int kh=0; kh<4; kh++){
      short8 bfr[4][2];
      #pragma unroll
      for (int kw=0; kw<4; kw++)
        #pragma unroll
        for (int ss=0; ss<2; ss++){
          int X = sh*32 + ss*16 + n15;
          bfr[kw][ss] = *(const short8*)&lds[((((quad*4 + kh)*2 + (kw&1))*CPH) + X + (kw>>1))*8];
        }
      #pragma unroll
      for (int kw=0; kw<4; kw++){
        int tap = kh*4 + kw;
        #pragma unroll
        for (int cs=0; cs<2; cs++){
          int co16 = (co_base + cs*16) >> 4;
          short8 af = *(const short8*)(wb +
              ((((size_t)tap*nco16 + co16)*nci32 + ci32)*64 + lane)*8);
          #pragma unroll
          for (int ss=0; ss<2; ss++)
            acc[cs][ss] = __builtin_amdgcn_mfma_f32_16x16x32_bf16(af, bfr[kw][ss], acc[cs][ss], 0,0,0);
        }
      }
    }
  };

  int nch = Cin >> 5;
  stage(ldsA, 0);
  __syncthreads();
  for (int t = 0; t < nch; t++){
    const short* cur = (t & 1) ? ldsB : ldsA;
    short*       nxt = (t & 1) ? ldsA : ldsB;
    if (t+1 < nch) stage(nxt, (t+1)*32);
    compute(cur, t*32);
    __syncthreads();
  }

  #pragma unroll
  for (int cs=0; cs<2; cs++)
    #pragma unroll
    for (int ss=0; ss<2; ss++){
      int jj = j0 + sh*32 + ss*16 + n15;
      short4v pk;
      #pragma unroll
      for (int r=0;r<4;r++) pk[r] = (short)bfbits(fmaxf(acc[cs][ss][r], 0.f));
      *(short4v*)&y[(((size_t)nimg*Hout + oh)*Wout + jj)*Cout + co_base + cs*16 + quad*4] = pk;
    }
}

// ---------------- proj: 1x1 conv as MFMA GEMM; z -> NCHW f32 (d_out) + NHWC f32 (ws) ----------------
// wb fragment order: [4 co16][16 ci32][64][8]
__global__ __launch_bounds__(256) void proj_mfma(
    const short* __restrict__ x, const short* __restrict__ wb,
    const float* __restrict__ bias, float* __restrict__ z_nchw,
    float* __restrict__ z_nhwc)
{
  int tid = threadIdx.x;
  int w = tid >> 6, lane = tid & 63;
  int n15 = lane & 15, quad = lane >> 4;
  int sp0 = blockIdx.x*64 + w*16;
  int nimg = blockIdx.y;
  f32x4 acc[4];
  #pragma unroll
  for (int cs=0; cs<4; cs++){
    int cb = cs*16 + quad*4;
    acc[cs] = f32x4{bias[cb], bias[cb+1], bias[cb+2], bias[cb+3]};
  }
  const short* xs = x + ((size_t)nimg*1024 + sp0 + n15)*512;
  for (int ci0=0; ci0<512; ci0+=32){
    short8 bfr = *(const short8*)(xs + ci0 + quad*8);
    #pragma unroll
    for (int cs=0; cs<4; cs++){
      short8 af = *(const short8*)(wb + ((((size_t)cs*16) + (ci0>>5))*64 + lane)*8);
      acc[cs] = __builtin_amdgcn_mfma_f32_16x16x32_bf16(af, bfr, acc[cs], 0,0,0);
    }
  }
  int sp = sp0 + n15;
  #pragma unroll
  for (int cs=0; cs<4; cs++){
    #pragma unroll
    for (int r=0;r<4;r++)
      z_nchw[(size_t)nimg*65536 + (size_t)(cs*16+quad*4+r)*1024 + sp] = acc[cs][r];
    *(f32x4*)&z_nhwc[((size_t)nimg*1024 + sp)*64 + cs*16 + quad*4] = acc[cs];
  }
}

// ---------------- VQ: per-wave argmin over 1024 codes (NHWC z) ----------------
// cbT [64 dims][1024 codes]: lane l owns codes g*256+4l..+3 -> float4 loads at
// base+lane*16B, fully coalesced.  Distance accumulates dims 0..63 in one
// sequential fmaf chain (same order as before) -> bitwise-identical distances.
__global__ void vq_argmin(const float* __restrict__ zf, const float* __restrict__ cbf,
                          const float* __restrict__ cbT,
                          float* __restrict__ zq, short* __restrict__ zqst)
{
  __shared__ float lz[4][64];
  int t = threadIdx.x;
  int q = t >> 6, l = t & 63;
  int p = blockIdx.x*4 + q;
  int n = p >> 10, hw = p & 1023;
  size_t nhbase = ((size_t)n*1024 + hw)*64;
  float zl = zf[nhbase + l];
  lz[q][l] = zl;
  __syncthreads();
  const float* zv = &lz[q][0];

  f32x4 acc[4];
  #pragma unroll
  for (int g=0; g<4; g++) acc[g] = f32x4{0.f,0.f,0.f,0.f};
  const float* rowb = cbT + l*4;
  for (int d = 0; d < 64; d++){
    float zd = zv[d];
    const float* row = rowb + (size_t)d*1024;
    #pragma unroll
    for (int g=0; g<4; g++){
      float4 cv = *(const float4*)(row + g*256);
      float t0 = zd - cv.x; acc[g][0] = fmaf(t0,t0,acc[g][0]);
      float t1 = zd - cv.y; acc[g][1] = fmaf(t1,t1,acc[g][1]);
      float t2 = zd - cv.z; acc[g][2] = fmaf(t2,t2,acc[g][2]);
      float t3 = zd - cv.w; acc[g][3] = fmaf(t3,t3,acc[g][3]);
    }
  }
  // per-lane scan in ascending code order (strict < keeps earliest index)
  float best = 3.0e38f; int bi = 0;
  #pragma unroll
  for (int g=0; g<4; g++){
    int c0 = g*256 + l*4;
    #pragma unroll
    for (int j=0; j<4; j++)
      if (acc[g][j] < best){ best = acc[g][j]; bi = c0 + j; }
  }
  // cross-lane min with index tie-break (smaller index wins on equal distance)
  #pragma unroll
  for (int off = 32; off > 0; off >>= 1){
    float od = __shfl_down(best, off, 64);
    int   oi = __shfl_down(bi,  off, 64);
    if (od < best || (od == best && oi < bi)){ best = od; bi = oi; }
  }
  bi = __shfl(bi, 0, 64);
  float qv = cbf[(size_t)bi*64 + l];
  zq[(size_t)n*65536 + (size_t)l*1024 + hw] = qv;
  zqst[nhbase + l] = (short)bfbits(zl + (qv - zl));
}

// ---------------- decoder: convT k=4 s=2 MFMA, NHWC — PHASE-SPLIT ----------------
// One block per sub-pixel phase (ph,pw); fragment-order weights.
// LDS layout [q4][r][CPC][8]: consecutive lanes read consecutive 16B blocks ->
// bank-conflict-free.  Accumulation order identical to r0 -> bitwise-identical.
template<int TS>
__global__ __launch_bounds__(256) void convT_mfma(
    const short* __restrict__ x, const short* __restrict__ wb,
    const float* __restrict__ bias, short* __restrict__ y,
    int Cin, int Hin, int Win, int Cout, int relu)
{
  constexpr int SHW  = TS/32;
  constexpr int COB  = (4/SHW)*32;
  constexpr int CPC  = TS + 1;          // staged cols per phase
  __shared__ __align__(16) short ldsA[4*2*CPC*8];
  __shared__ __align__(16) short ldsB[4*2*CPC*8];

  int tid = threadIdx.x;
  int w = tid >> 6, lane = tid & 63;
  int sh = w % SHW, ch = w / SHW;
  int n15 = lane & 15, quad = lane >> 4;
  int i0 = blockIdx.y;
  int j0 = blockIdx.x * TS;
  int nct = Cout / COB;
  int zz = blockIdx.z;
  int ph = (zz >> 1) & 1, pw = zz & 1;
  int ct = (zz >> 2) % nct;
  int nimg = (zz >> 2) / nct;
  int co_base = ct*COB + ch*32;
  int nco16 = Cout >> 4, nci32 = Cin >> 5;

  f32x4 acc[2][2];
  #pragma unroll
  for (int cs=0; cs<2; cs++){
    int cb = co_base + cs*16 + quad*4;
    f32x4 bv = {bias[cb], bias[cb+1], bias[cb+2], bias[cb+3]};
    acc[cs][0] = bv; acc[cs][1] = bv;
  }

  const short* xn = x + (size_t)nimg*Hin*Win*Cin;
  int row_org = i0 - 1 + ph;
  int col_org = j0 - 1 + pw;

  auto stage = [&](short* dst, int ci0){
    for (int idx = tid; idx < 2*CPC*4; idx += 256){
      int r   = idx / (CPC*4);
      int rem = idx - r*(CPC*4);
      int c   = rem >> 2;
      int q4  = rem & 3;
      int gi = row_org + r, gj = col_org + c;
      short8 v = {0,0,0,0,0,0,0,0};
      if ((unsigned)gi < (unsigned)Hin && (unsigned)gj < (unsigned)Win)
        v = *(const short8*)(xn + ((size_t)gi*Win + gj)*Cin + ci0 + q4*8);
      *(short8*)&dst[((q4*2 + r)*CPC + c)*8] = v;
    }
  };

  auto compute = [&](const short* lds, int ci0){
    int ci32 = ci0 >> 5;
    short8 br[2][2][2];               // [u][v][ss]
    #pragma unroll
    for (int u=0; u<2; u++)
      #pragma unroll
      for (int v=0; v<2; v++)
        #pragma unroll
        for (int ss=0; ss<2; ss++){
          int col = sh*32 + ss*16 + n15 + v;
          br[u][v][ss] = *(const short8*)&lds[((quad*2 + u)*CPC + col)*8];
        }
    #pragma unroll
    for (int u=0; u<2; u++)
      #pragma unroll
      for (int v=0; v<2; v++){
        int tap = (ph + 2*u)*4 + (pw + 2*v);
        #pragma unroll
        for (int cs=0; cs<2; cs++){
          int co16 = (co_base + cs*16) >> 4;
          short8 af = *(const short8*)(wb +
              ((((size_t)tap*nco16 + co16)*nci32 + ci32)*64 + lane)*8);
          #pragma unroll
          for (int ss=0; ss<2; ss++)
            acc[cs][ss] = __builtin_amdgcn_mfma_f32_16x16x32_bf16(af, br[u][v][ss], acc[cs][ss], 0,0,0);
        }
      }
  };

  int nch = Cin >> 5;
  stage(ldsA, 0);
  __syncthreads();
  for (int t = 0; t < nch; t++){
    const short* cur = (t & 1) ? ldsB : ldsA;
    short*       nxt = (t & 1) ? ldsA : ldsB;
    if (t+1 < nch) stage(nxt, (t+1)*32);
    compute(cur, t*32);
    __syncthreads();
  }

  int Hout = Hin*2, Wout = Win*2;
  #pragma unroll
  for (int cs=0; cs<2; cs++)
    #pragma unroll
    for (int ss=0; ss<2; ss++){
      int jj = j0 + sh*32 + ss*16 + n15;
      short4v pk;
      #pragma unroll
      for (int r=0;r<4;r++){
        float v2 = acc[cs][ss][r];
        if (relu) v2 = fmaxf(v2, 0.f);
        pk[r] = (short)bfbits(v2);
      }
      *(short4v*)&y[(((size_t)nimg*Hout + 2*i0+ph)*Wout + 2*jj+pw)*Cout + co_base + cs*16 + quad*4] = pk;
    }
}

// ---------------- out conv: 3x3 p=1 s=1, NHWC in -> NCHW f32 out ----------------
__global__ __launch_bounds__(256) void conv3x3_out3(
    const short* __restrict__ x, const float* __restrict__ wct,  // [ci][9][3]
    const float* __restrict__ bias, float* __restrict__ y)
{
  __shared__ __align__(16) short xl[6*66*16];
  int tid = threadIdx.x;
  int row = tid >> 6;
  int col = tid & 63;
  int j0 = blockIdx.x*64;
  int r0 = blockIdx.y*4;
  int n  = blockIdx.z;
  const short* xn = x + (size_t)n*65536*128;
  float acc[3] = {bias[0], bias[1], bias[2]};
  for (int g=0; g<8; g++){
    int cig = g*16;
    __syncthreads();
    for (int idx = tid; idx < 792; idx += 256){
      int r = idx / 132;
      int rem = idx - r*132;
      int c = rem >> 1;
      int h = rem & 1;
      int gi = r0 - 1 + r, gj = j0 - 1 + c;
      short8 v = {0,0,0,0,0,0,0,0};
      if ((unsigned)gi < 256u && (unsigned)gj < 256u)
        v = *(const short8*)(xn + ((size_t)gi*256 + gj)*128 + cig + h*8);
      *(short8*)&xl[(r*66 + c)*16 + h*8] = v;
    }
    __syncthreads();
    #pragma unroll
    for (int half=0; half<2; half++){
      short8 xv[9];
      #pragma unroll
      for (int dr=0; dr<3; dr++)
        #pragma unroll
        for (int dc=0; dc<3; dc++)
          xv[dr*3+dc] = *(const short8*)&xl[((row+dr)*66 + col+dc)*16 + half*8];
      #pragma unroll
      for (int k=0;k<8;k++){
        const float* wr = wct + (size_t)(cig + half*8 + k)*27;   // uniform
        #pragma unroll
        for (int tp=0; tp<9; tp++){
          float xf = bs2f(xv[tp][k]);
          acc[0] = fmaf(xf, wr[tp*3+0], acc[0]);
          acc[1] = fmaf(xf, wr[tp*3+1], acc[1]);
          acc[2] = fmaf(xf, wr[tp*3+2], acc[2]);
        }
      }
    }
  }
  size_t obase = (size_t)n*3*65536 + (size_t)(r0+row)*256 + j0 + col;
  y[obase]          = acc[0];
  y[obase + 65536]  = acc[1];
  y[obase + 131072] = acc[2];
}

// ---------------- workspace layout (bytes) ----------------
static const size_t W_WENC0  = 0;           //  24,576 f32 [tap][ci][co]
static const size_t W_WPROJB = 24576;       //  65,536 bf16 fragment-order
static const size_t W_WOUT   = 90112;       //  13,824 f32 [ci][tap][co]
static const size_t W_E1B    = 103936;      //  1,048,576 bf16 fragment-order
static const size_t W_E2B    = 1152512;     //  4,194,304
static const size_t W_D0B    = 5346816;     //  1,048,576
static const size_t W_D1B    = 6395392;     //  4,194,304
static const size_t W_D2B    = 10589696;    //  1,048,576
static const size_t W_CBT    = 11638272;    //  262,144 f32 codebook^T [64][1024]
static const size_t W_BYTES  = 11900416;
// per-image activations (NHWC, lifetime-aliased):
//   A 16MiB (h0 4M / d2 16M), Bg 8MiB (h1 2M / d1 8M), C 4MiB (h2 1M / d0 4M),
//   zf f32 256K, zqs bf16 128K
static const size_t PER_IMG = 29753344;

extern "C" void kernel_launch(void* const* d_in, const int* in_sizes, int n_in,
                              void* d_out, int out_size, void* d_ws, size_t ws_size,
                              hipStream_t stream)
{
  const float* x      = (const float*)d_in[0];
  const float* enc_w0 = (const float*)d_in[1];
  const float* enc_b0 = (const float*)d_in[2];
  const float* enc_w1 = (const float*)d_in[3];
  const float* enc_b1 = (const float*)d_in[4];
  const float* enc_w2 = (const float*)d_in[5];
  const float* enc_b2 = (const float*)d_in[6];
  const float* proj_w = (const float*)d_in[7];
  const float* proj_b = (const float*)d_in[8];
  const float* dec_w0 = (const float*)d_in[9];
  const float* dec_b0 = (const float*)d_in[10];
  const float* dec_w1 = (const float*)d_in[11];
  const float* dec_b1 = (const float*)d_in[12];
  const float* dec_w2 = (const float*)d_in[13];
  const float* dec_b2 = (const float*)d_in[14];
  const float* out_w  = (const float*)d_in[15];
  const float* out_b  = (const float*)d_in[16];
  const float* cb     = (const float*)d_in[17];

  float* out    = (float*)d_out;
  float* recon  = out;
  float* z_out  = out + 3145728;
  float* zq_out = out + 4194304;

  char* ws = (char*)d_ws;
  float* wenc0  = (float*)(ws + W_WENC0);
  short* wprojb = (short*)(ws + W_WPROJB);
  float* wout   = (float*)(ws + W_WOUT);
  short* we1b   = (short*)(ws + W_E1B);
  short* we2b   = (short*)(ws + W_E2B);
  short* wd0b   = (short*)(ws + W_D0B);
  short* wd1b   = (short*)(ws + W_D1B);
  short* wd2b   = (short*)(ws + W_D2B);
  float* cbT    = (float*)(ws + W_CBT);

  int B = 16;
  while (B > 1 && W_BYTES + (size_t)B*PER_IMG > ws_size) B >>= 1;

  char* act = ws + W_BYTES;
  size_t szA  = (size_t)B*16777216;
  size_t szBg = (size_t)B*8388608;
  size_t szC  = (size_t)B*4194304;
  short* h0  = (short*)(act);
  short* d2  = (short*)(act);
  short* h1  = (short*)(act + szA);
  short* d1  = (short*)(act + szA);
  short* h2  = (short*)(act + szA + szBg);
  short* d0  = (short*)(act + szA + szBg);
  float* zf  = (float*)(act + szA + szBg + szC);
  short* zqs = (short*)(act + szA + szBg + szC + (size_t)B*262144);

  // single fused repack launch (replaces 9 separate launches)
  repack_all<<<dim3(4096), 256, 0, stream>>>(
      enc_w0, wenc0, out_w, wout, proj_w, wprojb,
      enc_w1, we1b, enc_w2, we2b, dec_w0, wd0b, dec_w1, wd1b, dec_w2, wd2b,
      cb, cbT);

  for (int n0 = 0; n0 < 16; n0 += B){
    const float* xc  = x      + (size_t)n0*3*65536;
    float* reconc    = recon  + (size_t)n0*3*65536;
    float* z_outc    = z_out  + (size_t)n0*65536;
    float* zq_outc   = zq_out + (size_t)n0*65536;

    // encoder (NHWC activations)
    conv_enc0<<<dim3(16,16,B), 256, 0, stream>>>(xc, wenc0, enc_b0, h0);
    conv_enc_mfma<32><<<dim3(2, 64, B*2), 256, 0, stream>>>(
        h0, we1b, enc_b1, h1, 128, 128, 128, 256);
    conv_enc_mfma<32><<<dim3(1, 32, B*4), 256, 0, stream>>>(
        h1, we2b, enc_b2, h2, 256, 64, 64, 512);
    proj_mfma<<<dim3(16, B), 256, 0, stream>>>(h2, wprojb, proj_b, z_outc, zf);

    vq_argmin<<<dim3(256*B), 256, 0, stream>>>(zf, cb, cbT, zq_outc, zqs);

    // decoder (NHWC), phase-split: z = B * nct * 4 phases
    convT_mfma<32><<<dim3(1, 32, B*4*4), 256, 0, stream>>>(
        zqs, wd0b, dec_b0, d0, 64, 32, 32, 512, 1);      // nct=4 (COB=128)
    convT_mfma<64><<<dim3(1, 64, B*4*4), 256, 0, stream>>>(
        d0, wd1b, dec_b1, d1, 512, 64, 64, 256, 1);      // nct=4 (COB=64)
    convT_mfma<64><<<dim3(2, 128, B*2*4), 256, 0, stream>>>(
        d1, wd2b, dec_b2, d2, 256, 128, 128, 128, 1);    // nct=2 (COB=64)

    conv3x3_out3<<<dim3(4, 64, B), 256, 0, stream>>>(d2, wout, out_b, reconc);
  }
}

// Round 13
// 1792.298 us; speedup vs baseline: 1.1500x; 1.0825x over previous
//
#include <hip/hip_runtime.h>
#include <hip/hip_bf16.h>

typedef __hip_bfloat16 bf16;
typedef __attribute__((ext_vector_type(8))) short short8;
typedef __attribute__((ext_vector_type(4))) short short4v;
typedef __attribute__((ext_vector_type(4))) float f32x4;

__device__ __forceinline__ bf16 f2b(float v){ return __float2bfloat16(v); }
__device__ __forceinline__ unsigned short bfbits(float v){
  union{ bf16 h; unsigned short u; } t; t.h = f2b(v); return t.u;
}
__device__ __forceinline__ float bs2f(short s){
  union{ unsigned u; float f; } t; t.u = ((unsigned)(unsigned short)s) << 16; return t.f;
}

// ---------------- fused weight repack (single launch, 9 jobs) ----------------
// MFMA A-operand fragment order: [tap][Cout/16][Cin/32][64 lanes][8] bf16,
// lane l = quad*16+n15 holds co=co16*16+n15, ci=ci32*32+quad*8+e.
__device__ __forceinline__ void frag_one(const float* __restrict__ w, short* __restrict__ o,
                                         int Cout, int Cin, int KK, int i){
  int co = i / (Cin*KK);
  int r  = i - co*(Cin*KK);
  int ci = r / KK;
  int t  = r - ci*KK;
  int co16 = co >> 4, n15 = co & 15;
  int ci32 = ci >> 5, quad = (ci >> 3) & 3, e = ci & 7;
  size_t off = ((((size_t)t*(Cout>>4) + co16)*(Cin>>5) + ci32)*64 + (quad*16 + n15))*8 + e;
  o[off] = (short)bfbits(w[i]);
}

__global__ __launch_bounds__(256) void repack_all(
    const float* __restrict__ enc_w0, float* __restrict__ wenc0,
    const float* __restrict__ out_w,  float* __restrict__ wout,
    const float* __restrict__ proj_w, short* __restrict__ wprojb,
    const float* __restrict__ w_e1, short* __restrict__ we1b,
    const float* __restrict__ w_e2, short* __restrict__ we2b,
    const float* __restrict__ w_d0, short* __restrict__ wd0b,
    const float* __restrict__ w_d1, short* __restrict__ wd1b,
    const float* __restrict__ w_d2, short* __restrict__ wd2b,
    const float* __restrict__ cb,   float* __restrict__ cbT)
{
  int gid = blockIdx.x*256 + threadIdx.x;
  int stp = gridDim.x*256;

  // enc0: w[128][3][16] f32 -> [tap][ci][co] f32
  for (int i = gid; i < 128*3*16; i += stp){
    int co = i / 48, r = i - co*48, ci = r >> 4, t = r & 15;
    wenc0[((size_t)t*3 + ci)*128 + co] = enc_w0[i];
  }
  // out conv: w[3][128][9] f32 -> [ci][tap][co] f32
  for (int i = gid; i < 3*128*9; i += stp){
    int co = i / (128*9), r = i - co*(128*9), ci = r / 9, t = r - ci*9;
    wout[((size_t)ci*9 + t)*3 + co] = out_w[i];
  }
  // proj: [64][512] -> fragment order (KK=1)
  for (int i = gid; i < 64*512; i += stp) frag_one(proj_w, wprojb, 64, 512, 1, i);
  // enc1/enc2/dec0/dec1/dec2: fragment order (KK=16)
  for (int i = gid; i < 256*128*16; i += stp) frag_one(w_e1, we1b, 256, 128, 16, i);
  for (int i = gid; i < 512*256*16; i += stp) frag_one(w_e2, we2b, 512, 256, 16, i);
  for (int i = gid; i < 512*64*16;  i += stp) frag_one(w_d0, wd0b, 512, 64, 16, i);
  for (int i = gid; i < 256*512*16; i += stp) frag_one(w_d1, wd1b, 256, 512, 16, i);
  for (int i = gid; i < 128*256*16; i += stp) frag_one(w_d2, wd2b, 128, 256, 16, i);
  // codebook [1024][64] -> cbT [64][1024]
  for (int i = gid; i < 65536; i += stp){
    int c = i >> 6, d = i & 63;
    cbT[(size_t)d*1024 + c] = cb[i];
  }
}

// ---------------- enc0: conv k=4 s=2 p=1, NCHW f32 in -> NHWC bf16 out ----------------
__global__ __launch_bounds__(256) void conv_enc0(
    const float* __restrict__ x, const float* __restrict__ wp,  // [tap][ci][co]
    const float* __restrict__ bias, short* __restrict__ y)      // NHWC [128][128][128]
{
  int t = blockIdx.x*256 + threadIdx.x;
  int oh  = t >> 5;
  int ow0 = (t & 31) * 4;
  int co0 = blockIdx.y * 8;
  int n   = blockIdx.z;
  float acc[8][4];
  #pragma unroll
  for (int j=0;j<8;j++){
    float bv = bias[co0+j];
    #pragma unroll
    for (int o=0;o<4;o++) acc[j][o] = bv;
  }
  const float* xn = x + (size_t)n*3*65536;
  #pragma unroll
  for (int ci=0; ci<3; ci++){
    const float* xc = xn + (size_t)ci*65536;
    #pragma unroll
    for (int kh=0; kh<4; kh++){
      int ih = 2*oh - 1 + kh;
      float xv[12];
      if ((unsigned)ih < 256u){
        #pragma unroll
        for (int c2=0; c2<6; c2++){
          int col = 2*ow0 - 2 + 2*c2;
          if (col >= 0 && col < 256){
            float2 v = *(const float2*)(xc + (size_t)ih*256 + col);
            xv[2*c2] = v.x; xv[2*c2+1] = v.y;
          } else { xv[2*c2] = 0.f; xv[2*c2+1] = 0.f; }
        }
      } else {
        #pragma unroll
        for (int k=0;k<12;k++) xv[k] = 0.f;
      }
      #pragma unroll
      for (int kw=0; kw<4; kw++){
        const float* wr = wp + (size_t)((kh*4+kw)*3 + ci)*128 + co0;  // uniform
        #pragma unroll
        for (int j=0;j<8;j++){
          float wf = wr[j];
          #pragma unroll
          for (int o=0;o<4;o++)
            acc[j][o] = fmaf(xv[2*o+kw+1], wf, acc[j][o]);
        }
      }
    }
  }
  #pragma unroll
  for (int o=0;o<4;o++){
    short8 pk;
    #pragma unroll
    for (int j=0;j<8;j++) pk[j] = (short)bfbits(fmaxf(acc[j][o], 0.f));
    *(short8*)&y[(((size_t)n*128 + oh)*128 + (ow0+o))*128 + co0] = pk;
  }
}

// ---------------- enc1/enc2: conv k=4 s=2 p=1 MFMA, NHWC, 2cs x 2ss waves ----------------
// dbuf LDS, one barrier per chunk; fragment-order weights.
// LDS layout [q4][kh][parity][CPH][8]: stride-2 kw-reads become consecutive
// 16B blocks per lane -> bank-conflict-free ds_read_b128 / ds_write_b128.
template<int TS>
__global__ __launch_bounds__(256) void conv_enc_mfma(
    const short* __restrict__ x, const short* __restrict__ wb,
    const float* __restrict__ bias, short* __restrict__ y,
    int Cin, int Hin, int Win, int Cout)
{
  constexpr int SHW  = TS/32;
  constexpr int COB  = (4/SHW)*32;
  constexpr int CLS  = 2*TS + 2;
  constexpr int CPH  = TS + 1;
  __shared__ __align__(16) short ldsA[4*4*2*CPH*8];
  __shared__ __align__(16) short ldsB[4*4*2*CPH*8];

  int tid = threadIdx.x;
  int w = tid >> 6, lane = tid & 63;
  int sh = w % SHW, ch = w / SHW;
  int n15 = lane & 15, quad = lane >> 4;
  int oh = blockIdx.y;
  int j0 = blockIdx.x * TS;
  int nct = Cout / COB;
  int ct = blockIdx.z % nct;
  int nimg = blockIdx.z / nct;
  int co_base = ct*COB + ch*32;
  int Hout = Hin >> 1, Wout = Win >> 1;
  int row_org = 2*oh - 1;
  int col_org = 2*j0 - 1;
  int nco16 = Cout >> 4, nci32 = Cin >> 5;

  f32x4 acc[2][2];
  #pragma unroll
  for (int cs=0; cs<2; cs++){
    int cb = co_base + cs*16 + quad*4;
    f32x4 bv = {bias[cb], bias[cb+1], bias[cb+2], bias[cb+3]};
    acc[cs][0] = bv; acc[cs][1] = bv;
  }

  const short* xn = x + (size_t)nimg*Hin*Win*Cin;

  auto stage = [&](short* dst, int ci0){
    for (int idx = tid; idx < 4*CLS*4; idx += 256){
      int r   = idx / (CLS*4);
      int rem = idx - r*(CLS*4);
      int c   = rem >> 2;
      int q4  = rem & 3;
      int gi = row_org + r, gj = col_org + c;
      short8 v = {0,0,0,0,0,0,0,0};
      if ((unsigned)gi < (unsigned)Hin && (unsigned)gj < (unsigned)Win)
        v = *(const short8*)(xn + ((size_t)gi*Win + gj)*Cin + ci0 + q4*8);
      *(short8*)&dst[((((q4*4 + r)*2 + (c&1))*CPH) + (c>>1))*8] = v;
    }
  };

  auto compute = [&](const short* lds, int ci0){
    int ci32 = ci0 >> 5;
    #pragma unroll
    for (int kh=0; kh<4; kh++){
      short8 bfr[4][2];
      #pragma unroll
      for (int kw=0; kw<4; kw++)
        #pragma unroll
        for (int ss=0; ss<2; ss++){
          int X = sh*32 + ss*16 + n15;
          bfr[kw][ss] = *(const short8*)&lds[((((quad*4 + kh)*2 + (kw&1))*CPH) + X + (kw>>1))*8];
        }
      #pragma unroll
      for (int kw=0; kw<4; kw++){
        int tap = kh*4 + kw;
        #pragma unroll
        for (int cs=0; cs<2; cs++){
          int co16 = (co_base + cs*16) >> 4;
          short8 af = *(const short8*)(wb +
              ((((size_t)tap*nco16 + co16)*nci32 + ci32)*64 + lane)*8);
          #pragma unroll
          for (int ss=0; ss<2; ss++)
            acc[cs][ss] = __builtin_amdgcn_mfma_f32_16x16x32_bf16(af, bfr[kw][ss], acc[cs][ss], 0,0,0);
        }
      }
    }
  };

  int nch = Cin >> 5;
  stage(ldsA, 0);
  __syncthreads();
  for (int t = 0; t < nch; t++){
    const short* cur = (t & 1) ? ldsB : ldsA;
    short*       nxt = (t & 1) ? ldsA : ldsB;
    if (t+1 < nch) stage(nxt, (t+1)*32);
    compute(cur, t*32);
    __syncthreads();
  }

  #pragma unroll
  for (int cs=0; cs<2; cs++)
    #pragma unroll
    for (int ss=0; ss<2; ss++){
      int jj = j0 + sh*32 + ss*16 + n15;
      short4v pk;
      #pragma unroll
      for (int r=0;r<4;r++) pk[r] = (short)bfbits(fmaxf(acc[cs][ss][r], 0.f));
      *(short4v*)&y[(((size_t)nimg*Hout + oh)*Wout + jj)*Cout + co_base + cs*16 + quad*4] = pk;
    }
}

// ---------------- proj: 1x1 conv as MFMA GEMM; z -> NCHW f32 (d_out) + NHWC f32 (ws) ----------------
// wb fragment order: [4 co16][16 ci32][64][8]
__global__ __launch_bounds__(256) void proj_mfma(
    const short* __restrict__ x, const short* __restrict__ wb,
    const float* __restrict__ bias, float* __restrict__ z_nchw,
    float* __restrict__ z_nhwc)
{
  int tid = threadIdx.x;
  int w = tid >> 6, lane = tid & 63;
  int n15 = lane & 15, quad = lane >> 4;
  int sp0 = blockIdx.x*64 + w*16;
  int nimg = blockIdx.y;
  f32x4 acc[4];
  #pragma unroll
  for (int cs=0; cs<4; cs++){
    int cb = cs*16 + quad*4;
    acc[cs] = f32x4{bias[cb], bias[cb+1], bias[cb+2], bias[cb+3]};
  }
  const short* xs = x + ((size_t)nimg*1024 + sp0 + n15)*512;
  for (int ci0=0; ci0<512; ci0+=32){
    short8 bfr = *(const short8*)(xs + ci0 + quad*8);
    #pragma unroll
    for (int cs=0; cs<4; cs++){
      short8 af = *(const short8*)(wb + ((((size_t)cs*16) + (ci0>>5))*64 + lane)*8);
      acc[cs] = __builtin_amdgcn_mfma_f32_16x16x32_bf16(af, bfr, acc[cs], 0,0,0);
    }
  }
  int sp = sp0 + n15;
  #pragma unroll
  for (int cs=0; cs<4; cs++){
    #pragma unroll
    for (int r=0;r<4;r++)
      z_nchw[(size_t)nimg*65536 + (size_t)(cs*16+quad*4+r)*1024 + sp] = acc[cs][r];
    *(f32x4*)&z_nhwc[((size_t)nimg*1024 + sp)*64 + cs*16 + quad*4] = acc[cs];
  }
}

// ---------------- VQ: per-wave argmin over 1024 codes (NHWC z) ----------------
__global__ void vq_argmin(const float* __restrict__ zf, const float* __restrict__ cbf,
                          const float* __restrict__ cbT,
                          float* __restrict__ zq, short* __restrict__ zqst)
{
  __shared__ float lz[4][64];
  int t = threadIdx.x;
  int q = t >> 6, l = t & 63;
  int p = blockIdx.x*4 + q;
  int n = p >> 10, hw = p & 1023;
  size_t nhbase = ((size_t)n*1024 + hw)*64;
  float zl = zf[nhbase + l];
  lz[q][l] = zl;
  __syncthreads();
  const float* zv = &lz[q][0];

  f32x4 acc[4];
  #pragma unroll
  for (int g=0; g<4; g++) acc[g] = f32x4{0.f,0.f,0.f,0.f};
  const float* rowb = cbT + l*4;
  for (int d = 0; d < 64; d++){
    float zd = zv[d];
    const float* row = rowb + (size_t)d*1024;
    #pragma unroll
    for (int g=0; g<4; g++){
      float4 cv = *(const float4*)(row + g*256);
      float t0 = zd - cv.x; acc[g][0] = fmaf(t0,t0,acc[g][0]);
      float t1 = zd - cv.y; acc[g][1] = fmaf(t1,t1,acc[g][1]);
      float t2 = zd - cv.z; acc[g][2] = fmaf(t2,t2,acc[g][2]);
      float t3 = zd - cv.w; acc[g][3] = fmaf(t3,t3,acc[g][3]);
    }
  }
  // per-lane scan in ascending code order (strict < keeps earliest index)
  float best = 3.0e38f; int bi = 0;
  #pragma unroll
  for (int g=0; g<4; g++){
    int c0 = g*256 + l*4;
    #pragma unroll
    for (int j=0; j<4; j++)
      if (acc[g][j] < best){ best = acc[g][j]; bi = c0 + j; }
  }
  // cross-lane min with index tie-break (smaller index wins on equal distance)
  #pragma unroll
  for (int off = 32; off > 0; off >>= 1){
    float od = __shfl_down(best, off, 64);
    int   oi = __shfl_down(bi,  off, 64);
    if (od < best || (od == best && oi < bi)){ best = od; bi = oi; }
  }
  bi = __shfl(bi, 0, 64);
  float qv = cbf[(size_t)bi*64 + l];
  zq[(size_t)n*65536 + (size_t)l*1024 + hw] = qv;
  zqst[nhbase + l] = (short)bfbits(zl + (qv - zl));
}

// ---------------- decoder: convT k=4 s=2 MFMA, NHWC — PHASE-SPLIT, ROW-PAIR ----------------
// One block per sub-pixel phase (ph,pw) x input-row-PAIR (i0=2*by, i0+1): 3 staged
// rows (shared halo), each af weight fragment feeds 4 MFMAs (2 rows x 2 ss) ->
// halves L2 weight traffic per FLOP.  LDS [q4][r3][CPC][8] conflict-free.
// Accumulation order per output value identical to r0 -> bitwise-identical.
template<int TS>
__global__ __launch_bounds__(256) void convT_mfma(
    const short* __restrict__ x, const short* __restrict__ wb,
    const float* __restrict__ bias, short* __restrict__ y,
    int Cin, int Hin, int Win, int Cout, int relu)
{
  constexpr int SHW  = TS/32;
  constexpr int COB  = (4/SHW)*32;
  constexpr int CPC  = TS + 1;          // staged cols per phase
  constexpr int NST  = 3*CPC*4;         // 3 rows x CPC cols x 4 ci-octs
  __shared__ __align__(16) short ldsA[4*3*CPC*8];
  __shared__ __align__(16) short ldsB[4*3*CPC*8];

  int tid = threadIdx.x;
  int w = tid >> 6, lane = tid & 63;
  int sh = w % SHW, ch = w / SHW;
  int n15 = lane & 15, quad = lane >> 4;
  int i0 = blockIdx.y * 2;              // input-row pair
  int j0 = blockIdx.x * TS;
  int nct = Cout / COB;
  int zz = blockIdx.z;
  int ph = (zz >> 1) & 1, pw = zz & 1;
  int ct = (zz >> 2) % nct;
  int nimg = (zz >> 2) / nct;
  int co_base = ct*COB + ch*32;
  int nco16 = Cout >> 4, nci32 = Cin >> 5;

  f32x4 acc[2][2][2];                   // [rr][cs][ss]
  #pragma unroll
  for (int cs=0; cs<2; cs++){
    int cb = co_base + cs*16 + quad*4;
    f32x4 bv = {bias[cb], bias[cb+1], bias[cb+2], bias[cb+3]};
    #pragma unroll
    for (int rr=0; rr<2; rr++){ acc[rr][cs][0] = bv; acc[rr][cs][1] = bv; }
  }

  const short* xn = x + (size_t)nimg*Hin*Win*Cin;
  int row_org = i0 - 1 + ph;
  int col_org = j0 - 1 + pw;

  auto stage = [&](short* dst, int ci0){
    for (int idx = tid; idx < NST; idx += 256){
      int r   = idx / (CPC*4);
      int rem = idx - r*(CPC*4);
      int c   = rem >> 2;
      int q4  = rem & 3;
      int gi = row_org + r, gj = col_org + c;
      short8 v = {0,0,0,0,0,0,0,0};
      if ((unsigned)gi < (unsigned)Hin && (unsigned)gj < (unsigned)Win)
        v = *(const short8*)(xn + ((size_t)gi*Win + gj)*Cin + ci0 + q4*8);
      *(short8*)&dst[((q4*3 + r)*CPC + c)*8] = v;
    }
  };

  auto compute = [&](const short* lds, int ci0){
    int ci32 = ci0 >> 5;
    short8 b3[3][2][2];                 // [r3][v][ss]
    #pragma unroll
    for (int r3=0; r3<3; r3++)
      #pragma unroll
      for (int v=0; v<2; v++)
        #pragma unroll
        for (int ss=0; ss<2; ss++){
          int col = sh*32 + ss*16 + n15 + v;
          b3[r3][v][ss] = *(const short8*)&lds[((quad*3 + r3)*CPC + col)*8];
        }
    #pragma unroll
    for (int u=0; u<2; u++)
      #pragma unroll
      for (int v=0; v<2; v++){
        int tap = (ph + 2*u)*4 + (pw + 2*v);
        #pragma unroll
        for (int cs=0; cs<2; cs++){
          int co16 = (co_base + cs*16) >> 4;
          short8 af = *(const short8*)(wb +
              ((((size_t)tap*nco16 + co16)*nci32 + ci32)*64 + lane)*8);
          #pragma unroll
          for (int rr=0; rr<2; rr++)
            #pragma unroll
            for (int ss=0; ss<2; ss++)
              acc[rr][cs][ss] = __builtin_amdgcn_mfma_f32_16x16x32_bf16(af, b3[rr+u][v][ss], acc[rr][cs][ss], 0,0,0);
        }
      }
  };

  int nch = Cin >> 5;
  stage(ldsA, 0);
  __syncthreads();
  for (int t = 0; t < nch; t++){
    const short* cur = (t & 1) ? ldsB : ldsA;
    short*       nxt = (t & 1) ? ldsA : ldsB;
    if (t+1 < nch) stage(nxt, (t+1)*32);
    compute(cur, t*32);
    __syncthreads();
  }

  int Hout = Hin*2, Wout = Win*2;
  #pragma unroll
  for (int rr=0; rr<2; rr++)
    #pragma unroll
    for (int cs=0; cs<2; cs++)
      #pragma unroll
      for (int ss=0; ss<2; ss++){
        int jj = j0 + sh*32 + ss*16 + n15;
        short4v pk;
        #pragma unroll
        for (int r=0;r<4;r++){
          float v2 = acc[rr][cs][ss][r];
          if (relu) v2 = fmaxf(v2, 0.f);
          pk[r] = (short)bfbits(v2);
        }
        *(short4v*)&y[(((size_t)nimg*Hout + 2*(i0+rr)+ph)*Wout + 2*jj+pw)*Cout + co_base + cs*16 + quad*4] = pk;
      }
}

// ---------------- out conv: 3x3 p=1 s=1, NHWC in -> NCHW f32 out ----------------
__global__ __launch_bounds__(256) void conv3x3_out3(
    const short* __restrict__ x, const float* __restrict__ wct,  // [ci][9][3]
    const float* __restrict__ bias, float* __restrict__ y)
{
  __shared__ __align__(16) short xl[6*66*16];
  int tid = threadIdx.x;
  int row = tid >> 6;
  int col = tid & 63;
  int j0 = blockIdx.x*64;
  int r0 = blockIdx.y*4;
  int n  = blockIdx.z;
  const short* xn = x + (size_t)n*65536*128;
  float acc[3] = {bias[0], bias[1], bias[2]};
  for (int g=0; g<8; g++){
    int cig = g*16;
    __syncthreads();
    for (int idx = tid; idx < 792; idx += 256){
      int r = idx / 132;
      int rem = idx - r*132;
      int c = rem >> 1;
      int h = rem & 1;
      int gi = r0 - 1 + r, gj = j0 - 1 + c;
      short8 v = {0,0,0,0,0,0,0,0};
      if ((unsigned)gi < 256u && (unsigned)gj < 256u)
        v = *(const short8*)(xn + ((size_t)gi*256 + gj)*128 + cig + h*8);
      *(short8*)&xl[(r*66 + c)*16 + h*8] = v;
    }
    __syncthreads();
    #pragma unroll
    for (int half=0; half<2; half++){
      short8 xv[9];
      #pragma unroll
      for (int dr=0; dr<3; dr++)
        #pragma unroll
        for (int dc=0; dc<3; dc++)
          xv[dr*3+dc] = *(const short8*)&xl[((row+dr)*66 + col+dc)*16 + half*8];
      #pragma unroll
      for (int k=0;k<8;k++){
        const float* wr = wct + (size_t)(cig + half*8 + k)*27;   // uniform
        #pragma unroll
        for (int tp=0; tp<9; tp++){
          float xf = bs2f(xv[tp][k]);
          acc[0] = fmaf(xf, wr[tp*3+0], acc[0]);
          acc[1] = fmaf(xf, wr[tp*3+1], acc[1]);
          acc[2] = fmaf(xf, wr[tp*3+2], acc[2]);
        }
      }
    }
  }
  size_t obase = (size_t)n*3*65536 + (size_t)(r0+row)*256 + j0 + col;
  y[obase]          = acc[0];
  y[obase + 65536]  = acc[1];
  y[obase + 131072] = acc[2];
}

// ---------------- workspace layout (bytes) ----------------
static const size_t W_WENC0  = 0;           //  24,576 f32 [tap][ci][co]
static const size_t W_WPROJB = 24576;       //  65,536 bf16 fragment-order
static const size_t W_WOUT   = 90112;       //  13,824 f32 [ci][tap][co]
static const size_t W_E1B    = 103936;      //  1,048,576 bf16 fragment-order
static const size_t W_E2B    = 1152512;     //  4,194,304
static const size_t W_D0B    = 5346816;     //  1,048,576
static const size_t W_D1B    = 6395392;     //  4,194,304
static const size_t W_D2B    = 10589696;    //  1,048,576
static const size_t W_CBT    = 11638272;    //  262,144 f32 codebook^T [64][1024]
static const size_t W_BYTES  = 11900416;
// per-image activations (NHWC, lifetime-aliased):
//   A 16MiB (h0 4M / d2 16M), Bg 8MiB (h1 2M / d1 8M), C 4MiB (h2 1M / d0 4M),
//   zf f32 256K, zqs bf16 128K
static const size_t PER_IMG = 29753344;

extern "C" void kernel_launch(void* const* d_in, const int* in_sizes, int n_in,
                              void* d_out, int out_size, void* d_ws, size_t ws_size,
                              hipStream_t stream)
{
  const float* x      = (const float*)d_in[0];
  const float* enc_w0 = (const float*)d_in[1];
  const float* enc_b0 = (const float*)d_in[2];
  const float* enc_w1 = (const float*)d_in[3];
  const float* enc_b1 = (const float*)d_in[4];
  const float* enc_w2 = (const float*)d_in[5];
  const float* enc_b2 = (const float*)d_in[6];
  const float* proj_w = (const float*)d_in[7];
  const float* proj_b = (const float*)d_in[8];
  const float* dec_w0 = (const float*)d_in[9];
  const float* dec_b0 = (const float*)d_in[10];
  const float* dec_w1 = (const float*)d_in[11];
  const float* dec_b1 = (const float*)d_in[12];
  const float* dec_w2 = (const float*)d_in[13];
  const float* dec_b2 = (const float*)d_in[14];
  const float* out_w  = (const float*)d_in[15];
  const float* out_b  = (const float*)d_in[16];
  const float* cb     = (const float*)d_in[17];

  float* out    = (float*)d_out;
  float* recon  = out;
  float* z_out  = out + 3145728;
  float* zq_out = out + 4194304;

  char* ws = (char*)d_ws;
  float* wenc0  = (float*)(ws + W_WENC0);
  short* wprojb = (short*)(ws + W_WPROJB);
  float* wout   = (float*)(ws + W_WOUT);
  short* we1b   = (short*)(ws + W_E1B);
  short* we2b   = (short*)(ws + W_E2B);
  short* wd0b   = (short*)(ws + W_D0B);
  short* wd1b   = (short*)(ws + W_D1B);
  short* wd2b   = (short*)(ws + W_D2B);
  float* cbT    = (float*)(ws + W_CBT);

  int B = 16;
  while (B > 1 && W_BYTES + (size_t)B*PER_IMG > ws_size) B >>= 1;

  char* act = ws + W_BYTES;
  size_t szA  = (size_t)B*16777216;
  size_t szBg = (size_t)B*8388608;
  size_t szC  = (size_t)B*4194304;
  short* h0  = (short*)(act);
  short* d2  = (short*)(act);
  short* h1  = (short*)(act + szA);
  short* d1  = (short*)(act + szA);
  short* h2  = (short*)(act + szA + szBg);
  short* d0  = (short*)(act + szA + szBg);
  float* zf  = (float*)(act + szA + szBg + szC);
  short* zqs = (short*)(act + szA + szBg + szC + (size_t)B*262144);

  // single fused repack launch (replaces 9 separate launches)
  repack_all<<<dim3(4096), 256, 0, stream>>>(
      enc_w0, wenc0, out_w, wout, proj_w, wprojb,
      enc_w1, we1b, enc_w2, we2b, dec_w0, wd0b, dec_w1, wd1b, dec_w2, wd2b,
      cb, cbT);

  for (int n0 = 0; n0 < 16; n0 += B){
    const float* xc  = x      + (size_t)n0*3*65536;
    float* reconc    = recon  + (size_t)n0*3*65536;
    float* z_outc    = z_out  + (size_t)n0*65536;
    float* zq_outc   = zq_out + (size_t)n0*65536;

    // encoder (NHWC activations)
    conv_enc0<<<dim3(16,16,B), 256, 0, stream>>>(xc, wenc0, enc_b0, h0);
    conv_enc_mfma<32><<<dim3(2, 64, B*2), 256, 0, stream>>>(
        h0, we1b, enc_b1, h1, 128, 128, 128, 256);
    conv_enc_mfma<32><<<dim3(1, 32, B*4), 256, 0, stream>>>(
        h1, we2b, enc_b2, h2, 256, 64, 64, 512);
    proj_mfma<<<dim3(16, B), 256, 0, stream>>>(h2, wprojb, proj_b, z_outc, zf);

    vq_argmin<<<dim3(256*B), 256, 0, stream>>>(zf, cb, cbT, zq_outc, zqs);

    // decoder (NHWC), phase-split + row-pair: grid.y = Hin/2
    convT_mfma<32><<<dim3(1, 16, B*4*4), 256, 0, stream>>>(
        zqs, wd0b, dec_b0, d0, 64, 32, 32, 512, 1);      // nct=4 (COB=128)
    convT_mfma<64><<<dim3(1, 32, B*4*4), 256, 0, stream>>>(
        d0, wd1b, dec_b1, d1, 512, 64, 64, 256, 1);      // nct=4 (COB=64)
    convT_mfma<64><<<dim3(2, 64, B*2*4), 256, 0, stream>>>(
        d1, wd2b, dec_b2, d2, 256, 128, 128, 128, 1);    // nct=2 (COB=64)

    conv3x3_out3<<<dim3(4, 64, B), 256, 0, stream>>>(d2, wout, out_b, reconc);
  }
}

// Round 14
// 1770.536 us; speedup vs baseline: 1.1641x; 1.0123x over previous
//
#include <hip/hip_runtime.h>
#include <hip/hip_bf16.h>

typedef __hip_bfloat16 bf16;
typedef __attribute__((ext_vector_type(8))) short short8;
typedef __attribute__((ext_vector_type(4))) short short4v;
typedef __attribute__((ext_vector_type(4))) float f32x4;

__device__ __forceinline__ bf16 f2b(float v){ return __float2bfloat16(v); }
__device__ __forceinline__ unsigned short bfbits(float v){
  union{ bf16 h; unsigned short u; } t; t.h = f2b(v); return t.u;
}
__device__ __forceinline__ float bs2f(short s){
  union{ unsigned u; float f; } t; t.u = ((unsigned)(unsigned short)s) << 16; return t.f;
}

// ---------------- fused weight repack (single launch, 9 jobs) ----------------
// MFMA A-operand fragment order: [tap][Cout/16][Cin/32][64 lanes][8] bf16,
// lane l = quad*16+n15 holds co=co16*16+n15, ci=ci32*32+quad*8+e.
__device__ __forceinline__ void frag_one(const float* __restrict__ w, short* __restrict__ o,
                                         int Cout, int Cin, int KK, int i){
  int co = i / (Cin*KK);
  int r  = i - co*(Cin*KK);
  int ci = r / KK;
  int t  = r - ci*KK;
  int co16 = co >> 4, n15 = co & 15;
  int ci32 = ci >> 5, quad = (ci >> 3) & 3, e = ci & 7;
  size_t off = ((((size_t)t*(Cout>>4) + co16)*(Cin>>5) + ci32)*64 + (quad*16 + n15))*8 + e;
  o[off] = (short)bfbits(w[i]);
}

__global__ __launch_bounds__(256) void repack_all(
    const float* __restrict__ enc_w0, float* __restrict__ wenc0,
    const float* __restrict__ out_w,  float* __restrict__ wout,
    const float* __restrict__ proj_w, short* __restrict__ wprojb,
    const float* __restrict__ w_e1, short* __restrict__ we1b,
    const float* __restrict__ w_e2, short* __restrict__ we2b,
    const float* __restrict__ w_d0, short* __restrict__ wd0b,
    const float* __restrict__ w_d1, short* __restrict__ wd1b,
    const float* __restrict__ w_d2, short* __restrict__ wd2b,
    const float* __restrict__ cb,   float* __restrict__ cbT)
{
  int gid = blockIdx.x*256 + threadIdx.x;
  int stp = gridDim.x*256;

  // enc0: w[128][3][16] f32 -> [tap][ci][co] f32
  for (int i = gid; i < 128*3*16; i += stp){
    int co = i / 48, r = i - co*48, ci = r >> 4, t = r & 15;
    wenc0[((size_t)t*3 + ci)*128 + co] = enc_w0[i];
  }
  // out conv: w[3][128][9] f32 -> [ci][tap][co] f32
  for (int i = gid; i < 3*128*9; i += stp){
    int co = i / (128*9), r = i - co*(128*9), ci = r / 9, t = r - ci*9;
    wout[((size_t)ci*9 + t)*3 + co] = out_w[i];
  }
  // proj: [64][512] -> fragment order (KK=1)
  for (int i = gid; i < 64*512; i += stp) frag_one(proj_w, wprojb, 64, 512, 1, i);
  // enc1/enc2/dec0/dec1/dec2: fragment order (KK=16)
  for (int i = gid; i < 256*128*16; i += stp) frag_one(w_e1, we1b, 256, 128, 16, i);
  for (int i = gid; i < 512*256*16; i += stp) frag_one(w_e2, we2b, 512, 256, 16, i);
  for (int i = gid; i < 512*64*16;  i += stp) frag_one(w_d0, wd0b, 512, 64, 16, i);
  for (int i = gid; i < 256*512*16; i += stp) frag_one(w_d1, wd1b, 256, 512, 16, i);
  for (int i = gid; i < 128*256*16; i += stp) frag_one(w_d2, wd2b, 128, 256, 16, i);
  // codebook [1024][64] -> cbT [64][1024]
  for (int i = gid; i < 65536; i += stp){
    int c = i >> 6, d = i & 63;
    cbT[(size_t)d*1024 + c] = cb[i];
  }
}

// ---------------- enc0: conv k=4 s=2 p=1, NCHW f32 in -> NHWC bf16 out ----------------
__global__ __launch_bounds__(256) void conv_enc0(
    const float* __restrict__ x, const float* __restrict__ wp,  // [tap][ci][co]
    const float* __restrict__ bias, short* __restrict__ y)      // NHWC [128][128][128]
{
  int t = blockIdx.x*256 + threadIdx.x;
  int oh  = t >> 5;
  int ow0 = (t & 31) * 4;
  int co0 = blockIdx.y * 8;
  int n   = blockIdx.z;
  float acc[8][4];
  #pragma unroll
  for (int j=0;j<8;j++){
    float bv = bias[co0+j];
    #pragma unroll
    for (int o=0;o<4;o++) acc[j][o] = bv;
  }
  const float* xn = x + (size_t)n*3*65536;
  #pragma unroll
  for (int ci=0; ci<3; ci++){
    const float* xc = xn + (size_t)ci*65536;
    #pragma unroll
    for (int kh=0; kh<4; kh++){
      int ih = 2*oh - 1 + kh;
      float xv[12];
      if ((unsigned)ih < 256u){
        #pragma unroll
        for (int c2=0; c2<6; c2++){
          int col = 2*ow0 - 2 + 2*c2;
          if (col >= 0 && col < 256){
            float2 v = *(const float2*)(xc + (size_t)ih*256 + col);
            xv[2*c2] = v.x; xv[2*c2+1] = v.y;
          } else { xv[2*c2] = 0.f; xv[2*c2+1] = 0.f; }
        }
      } else {
        #pragma unroll
        for (int k=0;k<12;k++) xv[k] = 0.f;
      }
      #pragma unroll
      for (int kw=0; kw<4; kw++){
        const float* wr = wp + (size_t)((kh*4+kw)*3 + ci)*128 + co0;  // uniform
        #pragma unroll
        for (int j=0;j<8;j++){
          float wf = wr[j];
          #pragma unroll
          for (int o=0;o<4;o++)
            acc[j][o] = fmaf(xv[2*o+kw+1], wf, acc[j][o]);
        }
      }
    }
  }
  #pragma unroll
  for (int o=0;o<4;o++){
    short8 pk;
    #pragma unroll
    for (int j=0;j<8;j++) pk[j] = (short)bfbits(fmaxf(acc[j][o], 0.f));
    *(short8*)&y[(((size_t)n*128 + oh)*128 + (ow0+o))*128 + co0] = pk;
  }
}

// ---------------- enc1/enc2: conv k=4 s=2 p=1 MFMA, NHWC — ROW-PAIR ----------------
// Block computes output rows (oh0, oh0+1): 6 staged input rows (2 shared),
// each af weight fragment feeds 4 MFMAs (2 rows x 2 ss) -> halves L2 weight
// traffic per FLOP.  LDS [q4][r6][parity][CPH][8] conflict-free (stride-2 reads
// map to consecutive 16B blocks).  Accumulation order unchanged -> bit-identical.
template<int TS>
__global__ __launch_bounds__(256) void conv_enc_mfma(
    const short* __restrict__ x, const short* __restrict__ wb,
    const float* __restrict__ bias, short* __restrict__ y,
    int Cin, int Hin, int Win, int Cout)
{
  constexpr int SHW  = TS/32;
  constexpr int COB  = (4/SHW)*32;
  constexpr int CLS  = 2*TS + 2;
  constexpr int CPH  = TS + 1;
  constexpr int NST  = 6*CLS*4;        // 6 rows x CLS cols x 4 ci-octs
  __shared__ __align__(16) short ldsA[4*6*2*CPH*8];
  __shared__ __align__(16) short ldsB[4*6*2*CPH*8];

  int tid = threadIdx.x;
  int w = tid >> 6, lane = tid & 63;
  int sh = w % SHW, ch = w / SHW;
  int n15 = lane & 15, quad = lane >> 4;
  int oh0 = blockIdx.y * 2;            // output-row pair
  int j0 = blockIdx.x * TS;
  int nct = Cout / COB;
  int ct = blockIdx.z % nct;
  int nimg = blockIdx.z / nct;
  int co_base = ct*COB + ch*32;
  int Hout = Hin >> 1, Wout = Win >> 1;
  int row_org = 2*oh0 - 1;
  int col_org = 2*j0 - 1;
  int nco16 = Cout >> 4, nci32 = Cin >> 5;

  f32x4 acc[2][2][2];                  // [rr][cs][ss]
  #pragma unroll
  for (int cs=0; cs<2; cs++){
    int cb = co_base + cs*16 + quad*4;
    f32x4 bv = {bias[cb], bias[cb+1], bias[cb+2], bias[cb+3]};
    #pragma unroll
    for (int rr=0; rr<2; rr++){ acc[rr][cs][0] = bv; acc[rr][cs][1] = bv; }
  }

  const short* xn = x + (size_t)nimg*Hin*Win*Cin;

  auto stage = [&](short* dst, int ci0){
    for (int idx = tid; idx < NST; idx += 256){
      int r   = idx / (CLS*4);
      int rem = idx - r*(CLS*4);
      int c   = rem >> 2;
      int q4  = rem & 3;
      int gi = row_org + r, gj = col_org + c;
      short8 v = {0,0,0,0,0,0,0,0};
      if ((unsigned)gi < (unsigned)Hin && (unsigned)gj < (unsigned)Win)
        v = *(const short8*)(xn + ((size_t)gi*Win + gj)*Cin + ci0 + q4*8);
      *(short8*)&dst[((((q4*6 + r)*2 + (c&1))*CPH) + (c>>1))*8] = v;
    }
  };

  auto compute = [&](const short* lds, int ci0){
    int ci32 = ci0 >> 5;
    #pragma unroll
    for (int kh=0; kh<4; kh++){
      #pragma unroll
      for (int kw=0; kw<4; kw++){
        short8 bfr[2][2];              // [rr][ss]
        #pragma unroll
        for (int rr=0; rr<2; rr++)
          #pragma unroll
          for (int ss=0; ss<2; ss++){
            int X = sh*32 + ss*16 + n15;
            bfr[rr][ss] = *(const short8*)&lds[((((quad*6 + (2*rr+kh))*2 + (kw&1))*CPH) + X + (kw>>1))*8];
          }
        int tap = kh*4 + kw;
        #pragma unroll
        for (int cs=0; cs<2; cs++){
          int co16 = (co_base + cs*16) >> 4;
          short8 af = *(const short8*)(wb +
              ((((size_t)tap*nco16 + co16)*nci32 + ci32)*64 + lane)*8);
          #pragma unroll
          for (int rr=0; rr<2; rr++)
            #pragma unroll
            for (int ss=0; ss<2; ss++)
              acc[rr][cs][ss] = __builtin_amdgcn_mfma_f32_16x16x32_bf16(af, bfr[rr][ss], acc[rr][cs][ss], 0,0,0);
        }
      }
    }
  };

  int nch = Cin >> 5;
  stage(ldsA, 0);
  __syncthreads();
  for (int t = 0; t < nch; t++){
    const short* cur = (t & 1) ? ldsB : ldsA;
    short*       nxt = (t & 1) ? ldsA : ldsB;
    if (t+1 < nch) stage(nxt, (t+1)*32);
    compute(cur, t*32);
    __syncthreads();
  }

  #pragma unroll
  for (int rr=0; rr<2; rr++)
    #pragma unroll
    for (int cs=0; cs<2; cs++)
      #pragma unroll
      for (int ss=0; ss<2; ss++){
        int jj = j0 + sh*32 + ss*16 + n15;
        short4v pk;
        #pragma unroll
        for (int r=0;r<4;r++) pk[r] = (short)bfbits(fmaxf(acc[rr][cs][ss][r], 0.f));
        *(short4v*)&y[(((size_t)nimg*Hout + oh0+rr)*Wout + jj)*Cout + co_base + cs*16 + quad*4] = pk;
      }
}

// ---------------- proj: 1x1 conv as MFMA GEMM; z -> NCHW f32 (d_out) + NHWC f32 (ws) ----------------
// wb fragment order: [4 co16][16 ci32][64][8]
__global__ __launch_bounds__(256) void proj_mfma(
    const short* __restrict__ x, const short* __restrict__ wb,
    const float* __restrict__ bias, float* __restrict__ z_nchw,
    float* __restrict__ z_nhwc)
{
  int tid = threadIdx.x;
  int w = tid >> 6, lane = tid & 63;
  int n15 = lane & 15, quad = lane >> 4;
  int sp0 = blockIdx.x*64 + w*16;
  int nimg = blockIdx.y;
  f32x4 acc[4];
  #pragma unroll
  for (int cs=0; cs<4; cs++){
    int cb = cs*16 + quad*4;
    acc[cs] = f32x4{bias[cb], bias[cb+1], bias[cb+2], bias[cb+3]};
  }
  const short* xs = x + ((size_t)nimg*1024 + sp0 + n15)*512;
  for (int ci0=0; ci0<512; ci0+=32){
    short8 bfr = *(const short8*)(xs + ci0 + quad*8);
    #pragma unroll
    for (int cs=0; cs<4; cs++){
      short8 af = *(const short8*)(wb + ((((size_t)cs*16) + (ci0>>5))*64 + lane)*8);
      acc[cs] = __builtin_amdgcn_mfma_f32_16x16x32_bf16(af, bfr, acc[cs], 0,0,0);
    }
  }
  int sp = sp0 + n15;
  #pragma unroll
  for (int cs=0; cs<4; cs++){
    #pragma unroll
    for (int r=0;r<4;r++)
      z_nchw[(size_t)nimg*65536 + (size_t)(cs*16+quad*4+r)*1024 + sp] = acc[cs][r];
    *(f32x4*)&z_nhwc[((size_t)nimg*1024 + sp)*64 + cs*16 + quad*4] = acc[cs];
  }
}

// ---------------- VQ: per-wave argmin over 1024 codes (NHWC z) ----------------
__global__ void vq_argmin(const float* __restrict__ zf, const float* __restrict__ cbf,
                          const float* __restrict__ cbT,
                          float* __restrict__ zq, short* __restrict__ zqst)
{
  __shared__ float lz[4][64];
  int t = threadIdx.x;
  int q = t >> 6, l = t & 63;
  int p = blockIdx.x*4 + q;
  int n = p >> 10, hw = p & 1023;
  size_t nhbase = ((size_t)n*1024 + hw)*64;
  float zl = zf[nhbase + l];
  lz[q][l] = zl;
  __syncthreads();
  const float* zv = &lz[q][0];

  f32x4 acc[4];
  #pragma unroll
  for (int g=0; g<4; g++) acc[g] = f32x4{0.f,0.f,0.f,0.f};
  const float* rowb = cbT + l*4;
  for (int d = 0; d < 64; d++){
    float zd = zv[d];
    const float* row = rowb + (size_t)d*1024;
    #pragma unroll
    for (int g=0; g<4; g++){
      float4 cv = *(const float4*)(row + g*256);
      float t0 = zd - cv.x; acc[g][0] = fmaf(t0,t0,acc[g][0]);
      float t1 = zd - cv.y; acc[g][1] = fmaf(t1,t1,acc[g][1]);
      float t2 = zd - cv.z; acc[g][2] = fmaf(t2,t2,acc[g][2]);
      float t3 = zd - cv.w; acc[g][3] = fmaf(t3,t3,acc[g][3]);
    }
  }
  // per-lane scan in ascending code order (strict < keeps earliest index)
  float best = 3.0e38f; int bi = 0;
  #pragma unroll
  for (int g=0; g<4; g++){
    int c0 = g*256 + l*4;
    #pragma unroll
    for (int j=0; j<4; j++)
      if (acc[g][j] < best){ best = acc[g][j]; bi = c0 + j; }
  }
  // cross-lane min with index tie-break (smaller index wins on equal distance)
  #pragma unroll
  for (int off = 32; off > 0; off >>= 1){
    float od = __shfl_down(best, off, 64);
    int   oi = __shfl_down(bi,  off, 64);
    if (od < best || (od == best && oi < bi)){ best = od; bi = oi; }
  }
  bi = __shfl(bi, 0, 64);
  float qv = cbf[(size_t)bi*64 + l];
  zq[(size_t)n*65536 + (size_t)l*1024 + hw] = qv;
  zqst[nhbase + l] = (short)bfbits(zl + (qv - zl));
}

// ---------------- decoder: convT k=4 s=2 MFMA, NHWC — PHASE-SPLIT, ROW-PAIR ----------------
// One block per sub-pixel phase (ph,pw) x input-row-PAIR (i0=2*by, i0+1): 3 staged
// rows (shared halo), each af weight fragment feeds 4 MFMAs (2 rows x 2 ss) ->
// halves L2 weight traffic per FLOP.  LDS [q4][r3][CPC][8] conflict-free.
// Accumulation order per output value identical to r0 -> bitwise-identical.
template<int TS>
__global__ __launch_bounds__(256) void convT_mfma(
    const short* __restrict__ x, const short* __restrict__ wb,
    const float* __restrict__ bias, short* __restrict__ y,
    int Cin, int Hin, int Win, int Cout, int relu)
{
  constexpr int SHW  = TS/32;
  constexpr int COB  = (4/SHW)*32;
  constexpr int CPC  = TS + 1;          // staged cols per phase
  constexpr int NST  = 3*CPC*4;         // 3 rows x CPC cols x 4 ci-octs
  __shared__ __align__(16) short ldsA[4*3*CPC*8];
  __shared__ __align__(16) short ldsB[4*3*CPC*8];

  int tid = threadIdx.x;
  int w = tid >> 6, lane = tid & 63;
  int sh = w % SHW, ch = w / SHW;
  int n15 = lane & 15, quad = lane >> 4;
  int i0 = blockIdx.y * 2;              // input-row pair
  int j0 = blockIdx.x * TS;
  int nct = Cout / COB;
  int zz = blockIdx.z;
  int ph = (zz >> 1) & 1, pw = zz & 1;
  int ct = (zz >> 2) % nct;
  int nimg = (zz >> 2) / nct;
  int co_base = ct*COB + ch*32;
  int nco16 = Cout >> 4, nci32 = Cin >> 5;

  f32x4 acc[2][2][2];                   // [rr][cs][ss]
  #pragma unroll
  for (int cs=0; cs<2; cs++){
    int cb = co_base + cs*16 + quad*4;
    f32x4 bv = {bias[cb], bias[cb+1], bias[cb+2], bias[cb+3]};
    #pragma unroll
    for (int rr=0; rr<2; rr++){ acc[rr][cs][0] = bv; acc[rr][cs][1] = bv; }
  }

  const short* xn = x + (size_t)nimg*Hin*Win*Cin;
  int row_org = i0 - 1 + ph;
  int col_org = j0 - 1 + pw;

  auto stage = [&](short* dst, int ci0){
    for (int idx = tid; idx < NST; idx += 256){
      int r   = idx / (CPC*4);
      int rem = idx - r*(CPC*4);
      int c   = rem >> 2;
      int q4  = rem & 3;
      int gi = row_org + r, gj = col_org + c;
      short8 v = {0,0,0,0,0,0,0,0};
      if ((unsigned)gi < (unsigned)Hin && (unsigned)gj < (unsigned)Win)
        v = *(const short8*)(xn + ((size_t)gi*Win + gj)*Cin + ci0 + q4*8);
      *(short8*)&dst[((q4*3 + r)*CPC + c)*8] = v;
    }
  };

  auto compute = [&](const short* lds, int ci0){
    int ci32 = ci0 >> 5;
    short8 b3[3][2][2];                 // [r3][v][ss]
    #pragma unroll
    for (int r3=0; r3<3; r3++)
      #pragma unroll
      for (int v=0; v<2; v++)
        #pragma unroll
        for (int ss=0; ss<2; ss++){
          int col = sh*32 + ss*16 + n15 + v;
          b3[r3][v][ss] = *(const short8*)&lds[((quad*3 + r3)*CPC + col)*8];
        }
    #pragma unroll
    for (int u=0; u<2; u++)
      #pragma unroll
      for (int v=0; v<2; v++){
        int tap = (ph + 2*u)*4 + (pw + 2*v);
        #pragma unroll
        for (int cs=0; cs<2; cs++){
          int co16 = (co_base + cs*16) >> 4;
          short8 af = *(const short8*)(wb +
              ((((size_t)tap*nco16 + co16)*nci32 + ci32)*64 + lane)*8);
          #pragma unroll
          for (int rr=0; rr<2; rr++)
            #pragma unroll
            for (int ss=0; ss<2; ss++)
              acc[rr][cs][ss] = __builtin_amdgcn_mfma_f32_16x16x32_bf16(af, b3[rr+u][v][ss], acc[rr][cs][ss], 0,0,0);
        }
      }
  };

  int nch = Cin >> 5;
  stage(ldsA, 0);
  __syncthreads();
  for (int t = 0; t < nch; t++){
    const short* cur = (t & 1) ? ldsB : ldsA;
    short*       nxt = (t & 1) ? ldsA : ldsB;
    if (t+1 < nch) stage(nxt, (t+1)*32);
    compute(cur, t*32);
    __syncthreads();
  }

  int Hout = Hin*2, Wout = Win*2;
  #pragma unroll
  for (int rr=0; rr<2; rr++)
    #pragma unroll
    for (int cs=0; cs<2; cs++)
      #pragma unroll
      for (int ss=0; ss<2; ss++){
        int jj = j0 + sh*32 + ss*16 + n15;
        short4v pk;
        #pragma unroll
        for (int r=0;r<4;r++){
          float v2 = acc[rr][cs][ss][r];
          if (relu) v2 = fmaxf(v2, 0.f);
          pk[r] = (short)bfbits(v2);
        }
        *(short4v*)&y[(((size_t)nimg*Hout + 2*(i0+rr)+ph)*Wout + 2*jj+pw)*Cout + co_base + cs*16 + quad*4] = pk;
      }
}

// ---------------- out conv: 3x3 p=1 s=1, NHWC in -> NCHW f32 out ----------------
__global__ __launch_bounds__(256) void conv3x3_out3(
    const short* __restrict__ x, const float* __restrict__ wct,  // [ci][9][3]
    const float* __restrict__ bias, float* __restrict__ y)
{
  __shared__ __align__(16) short xl[6*66*16];
  int tid = threadIdx.x;
  int row = tid >> 6;
  int col = tid & 63;
  int j0 = blockIdx.x*64;
  int r0 = blockIdx.y*4;
  int n  = blockIdx.z;
  const short* xn = x + (size_t)n*65536*128;
  float acc[3] = {bias[0], bias[1], bias[2]};
  for (int g=0; g<8; g++){
    int cig = g*16;
    __syncthreads();
    for (int idx = tid; idx < 792; idx += 256){
      int r = idx / 132;
      int rem = idx - r*132;
      int c = rem >> 1;
      int h = rem & 1;
      int gi = r0 - 1 + r, gj = j0 - 1 + c;
      short8 v = {0,0,0,0,0,0,0,0};
      if ((unsigned)gi < 256u && (unsigned)gj < 256u)
        v = *(const short8*)(xn + ((size_t)gi*256 + gj)*128 + cig + h*8);
      *(short8*)&xl[(r*66 + c)*16 + h*8] = v;
    }
    __syncthreads();
    #pragma unroll
    for (int half=0; half<2; half++){
      short8 xv[9];
      #pragma unroll
      for (int dr=0; dr<3; dr++)
        #pragma unroll
        for (int dc=0; dc<3; dc++)
          xv[dr*3+dc] = *(const short8*)&xl[((row+dr)*66 + col+dc)*16 + half*8];
      #pragma unroll
      for (int k=0;k<8;k++){
        const float* wr = wct + (size_t)(cig + half*8 + k)*27;   // uniform
        #pragma unroll
        for (int tp=0; tp<9; tp++){
          float xf = bs2f(xv[tp][k]);
          acc[0] = fmaf(xf, wr[tp*3+0], acc[0]);
          acc[1] = fmaf(xf, wr[tp*3+1], acc[1]);
          acc[2] = fmaf(xf, wr[tp*3+2], acc[2]);
        }
      }
    }
  }
  size_t obase = (size_t)n*3*65536 + (size_t)(r0+row)*256 + j0 + col;
  y[obase]          = acc[0];
  y[obase + 65536]  = acc[1];
  y[obase + 131072] = acc[2];
}

// ---------------- workspace layout (bytes) ----------------
static const size_t W_WENC0  = 0;           //  24,576 f32 [tap][ci][co]
static const size_t W_WPROJB = 24576;       //  65,536 bf16 fragment-order
static const size_t W_WOUT   = 90112;       //  13,824 f32 [ci][tap][co]
static const size_t W_E1B    = 103936;      //  1,048,576 bf16 fragment-order
static const size_t W_E2B    = 1152512;     //  4,194,304
static const size_t W_D0B    = 5346816;     //  1,048,576
static const size_t W_D1B    = 6395392;     //  4,194,304
static const size_t W_D2B    = 10589696;    //  1,048,576
static const size_t W_CBT    = 11638272;    //  262,144 f32 codebook^T [64][1024]
static const size_t W_BYTES  = 11900416;
// per-image activations (NHWC, lifetime-aliased):
//   A 16MiB (h0 4M / d2 16M), Bg 8MiB (h1 2M / d1 8M), C 4MiB (h2 1M / d0 4M),
//   zf f32 256K, zqs bf16 128K
static const size_t PER_IMG = 29753344;

extern "C" void kernel_launch(void* const* d_in, const int* in_sizes, int n_in,
                              void* d_out, int out_size, void* d_ws, size_t ws_size,
                              hipStream_t stream)
{
  const float* x      = (const float*)d_in[0];
  const float* enc_w0 = (const float*)d_in[1];
  const float* enc_b0 = (const float*)d_in[2];
  const float* enc_w1 = (const float*)d_in[3];
  const float* enc_b1 = (const float*)d_in[4];
  const float* enc_w2 = (const float*)d_in[5];
  const float* enc_b2 = (const float*)d_in[6];
  const float* proj_w = (const float*)d_in[7];
  const float* proj_b = (const float*)d_in[8];
  const float* dec_w0 = (const float*)d_in[9];
  const float* dec_b0 = (const float*)d_in[10];
  const float* dec_w1 = (const float*)d_in[11];
  const float* dec_b1 = (const float*)d_in[12];
  const float* dec_w2 = (const float*)d_in[13];
  const float* dec_b2 = (const float*)d_in[14];
  const float* out_w  = (const float*)d_in[15];
  const float* out_b  = (const float*)d_in[16];
  const float* cb     = (const float*)d_in[17];

  float* out    = (float*)d_out;
  float* recon  = out;
  float* z_out  = out + 3145728;
  float* zq_out = out + 4194304;

  char* ws = (char*)d_ws;
  float* wenc0  = (float*)(ws + W_WENC0);
  short* wprojb = (short*)(ws + W_WPROJB);
  float* wout   = (float*)(ws + W_WOUT);
  short* we1b   = (short*)(ws + W_E1B);
  short* we2b   = (short*)(ws + W_E2B);
  short* wd0b   = (short*)(ws + W_D0B);
  short* wd1b   = (short*)(ws + W_D1B);
  short* wd2b   = (short*)(ws + W_D2B);
  float* cbT    = (float*)(ws + W_CBT);

  int B = 16;
  while (B > 1 && W_BYTES + (size_t)B*PER_IMG > ws_size) B >>= 1;

  char* act = ws + W_BYTES;
  size_t szA  = (size_t)B*16777216;
  size_t szBg = (size_t)B*8388608;
  size_t szC  = (size_t)B*4194304;
  short* h0  = (short*)(act);
  short* d2  = (short*)(act);
  short* h1  = (short*)(act + szA);
  short* d1  = (short*)(act + szA);
  short* h2  = (short*)(act + szA + szBg);
  short* d0  = (short*)(act + szA + szBg);
  float* zf  = (float*)(act + szA + szBg + szC);
  short* zqs = (short*)(act + szA + szBg + szC + (size_t)B*262144);

  // single fused repack launch (replaces 9 separate launches)
  repack_all<<<dim3(4096), 256, 0, stream>>>(
      enc_w0, wenc0, out_w, wout, proj_w, wprojb,
      enc_w1, we1b, enc_w2, we2b, dec_w0, wd0b, dec_w1, wd1b, dec_w2, wd2b,
      cb, cbT);

  for (int n0 = 0; n0 < 16; n0 += B){
    const float* xc  = x      + (size_t)n0*3*65536;
    float* reconc    = recon  + (size_t)n0*3*65536;
    float* z_outc    = z_out  + (size_t)n0*65536;
    float* zq_outc   = zq_out + (size_t)n0*65536;

    // encoder (NHWC activations), row-pair: grid.y = Hout/2
    conv_enc0<<<dim3(16,16,B), 256, 0, stream>>>(xc, wenc0, enc_b0, h0);
    conv_enc_mfma<32><<<dim3(2, 32, B*2), 256, 0, stream>>>(
        h0, we1b, enc_b1, h1, 128, 128, 128, 256);
    conv_enc_mfma<32><<<dim3(1, 16, B*4), 256, 0, stream>>>(
        h1, we2b, enc_b2, h2, 256, 64, 64, 512);
    proj_mfma<<<dim3(16, B), 256, 0, stream>>>(h2, wprojb, proj_b, z_outc, zf);

    vq_argmin<<<dim3(256*B), 256, 0, stream>>>(zf, cb, cbT, zq_outc, zqs);

    // decoder (NHWC), phase-split + row-pair: grid.y = Hin/2
    convT_mfma<32><<<dim3(1, 16, B*4*4), 256, 0, stream>>>(
        zqs, wd0b, dec_b0, d0, 64, 32, 32, 512, 1);      // nct=4 (COB=128)
    convT_mfma<64><<<dim3(1, 32, B*4*4), 256, 0, stream>>>(
        d0, wd1b, dec_b1, d1, 512, 64, 64, 256, 1);      // nct=4 (COB=64)
    convT_mfma<64><<<dim3(2, 64, B*2*4), 256, 0, stream>>>(
        d1, wd2b, dec_b2, d2, 256, 128, 128, 128, 1);    // nct=2 (COB=64)

    conv3x3_out3<<<dim3(4, 64, B), 256, 0, stream>>>(d2, wout, out_b, reconc);
  }
}